// Round 1
// baseline (1998.086 us; speedup 1.0000x reference)
//
#include <hip/hip_runtime.h>
#include <hip/hip_bf16.h>
#include <cstdint>
#include <cstddef>

#define Bdim 4
#define Tdim 2048
#define Cdim 1024

// ---------------------------------------------------------------------------
// fp32 SGEMM, "NT" layout: C[m,n] = sum_k A[m*K+k] * B[n*K+k]
// (both operands row-major with K contiguous — matches both einsums here)
// 128x128 block tile, BK=16, 256 threads, 8x8 per thread (2x2 quads of 4x4).
// LDS tiles stored k-major (As[k][m]) with +4 pad: conflict-free ds_read_b128.
// ---------------------------------------------------------------------------
#define BM 128
#define BN 128
#define BK 16

__global__ __launch_bounds__(256) void sgemm_nt(
    const float* __restrict__ A, const float* __restrict__ B, float* __restrict__ C,
    int M, int N, int K)
{
    __shared__ float As[BK][BM + 4];
    __shared__ float Bs[BK][BN + 4];

    const int tid = threadIdx.x;
    const int m0 = blockIdx.y * BM;
    const int n0 = blockIdx.x * BN;
    const int tx = tid & 15;        // N-dir thread coord (0..15)
    const int ty = tid >> 4;        // M-dir thread coord (0..15)
    const int lc = tid & 3;         // loader k-quad (0..3)
    const int lr = tid >> 2;        // loader row (0..63)

    const float* Ap = A + (size_t)(m0 + lr) * K + 4 * lc;
    const float* Bp = B + (size_t)(n0 + lr) * K + 4 * lc;

    // software prefetch: stage tile k0=0 in registers
    float4 a0 = *(const float4*)(Ap);
    float4 a1 = *(const float4*)(Ap + (size_t)64 * K);
    float4 b0 = *(const float4*)(Bp);
    float4 b1 = *(const float4*)(Bp + (size_t)64 * K);

    float acc[2][2][4][4] = {};

    for (int k0 = 0; k0 < K; k0 += BK) {
        __syncthreads();
        // store staged tile to LDS, transposed to k-major
        #pragma unroll
        for (int j = 0; j < 4; ++j) {
            As[4 * lc + j][lr]      = ((const float*)&a0)[j];
            As[4 * lc + j][64 + lr] = ((const float*)&a1)[j];
            Bs[4 * lc + j][lr]      = ((const float*)&b0)[j];
            Bs[4 * lc + j][64 + lr] = ((const float*)&b1)[j];
        }
        __syncthreads();

        // issue next tile's global loads; they complete under the FMA loop
        if (k0 + BK < K) {
            Ap += BK; Bp += BK;
            a0 = *(const float4*)(Ap);
            a1 = *(const float4*)(Ap + (size_t)64 * K);
            b0 = *(const float4*)(Bp);
            b1 = *(const float4*)(Bp + (size_t)64 * K);
        }

        #pragma unroll
        for (int kk = 0; kk < BK; ++kk) {
            float4 av0 = *(const float4*)&As[kk][4 * ty];
            float4 av1 = *(const float4*)&As[kk][64 + 4 * ty];
            float4 bv0 = *(const float4*)&Bs[kk][4 * tx];
            float4 bv1 = *(const float4*)&Bs[kk][64 + 4 * tx];
            const float* ap0 = (const float*)&av0;
            const float* ap1 = (const float*)&av1;
            const float* bp0 = (const float*)&bv0;
            const float* bp1 = (const float*)&bv1;
            #pragma unroll
            for (int p = 0; p < 4; ++p) {
                #pragma unroll
                for (int q = 0; q < 4; ++q) {
                    acc[0][0][p][q] += ap0[p] * bp0[q];
                    acc[0][1][p][q] += ap0[p] * bp1[q];
                    acc[1][0][p][q] += ap1[p] * bp0[q];
                    acc[1][1][p][q] += ap1[p] * bp1[q];
                }
            }
        }
    }

    #pragma unroll
    for (int mh = 0; mh < 2; ++mh) {
        #pragma unroll
        for (int p = 0; p < 4; ++p) {
            const int m = m0 + mh * 64 + 4 * ty + p;
            #pragma unroll
            for (int nh = 0; nh < 2; ++nh) {
                float4 v;
                v.x = acc[mh][nh][p][0];
                v.y = acc[mh][nh][p][1];
                v.z = acc[mh][nh][p][2];
                v.w = acc[mh][nh][p][3];
                *(float4*)&C[(size_t)m * N + n0 + nh * 64 + 4 * tx] = v;
            }
        }
    }
}

// ---------------------------------------------------------------------------
// Fused sigmoid(r) * WKV scan, both directions.
// rkv layout: [B, T, 2, 3, C]  (dir, {r,k,v})
// out: out_cat [B, T, 2C]  (forward dir in [0,C), backward in [C,2C))
// One thread per (b, dir, c). Depth-4 register prefetch over t.
// ---------------------------------------------------------------------------
__global__ __launch_bounds__(256) void wkv_scan(
    const float* __restrict__ rkv,
    const float* __restrict__ td,  const float* __restrict__ tf,
    const float* __restrict__ tdr, const float* __restrict__ tfr,
    float* __restrict__ outcat)
{
    const int tid = threadIdx.x;
    const int bi  = blockIdx.x;
    const int b   = bi >> 3;
    const int rem = bi & 7;
    const int dir = rem >> 2;
    const int c   = (rem & 3) * 256 + tid;

    const float w = -__expf(dir ? tdr[c] : td[c]);
    const float u = dir ? tfr[c] : tf[c];

    const int strideT = 6 * Cdim;
    const int tstart  = dir ? (Tdim - 1) : 0;
    const int tstep   = dir ? -strideT : strideT;
    const int ostep   = dir ? -(2 * Cdim) : (2 * Cdim);

    const float* p = rkv + ((size_t)b * Tdim + tstart) * strideT + dir * 3 * Cdim + c;
    float* po = outcat + ((size_t)b * Tdim + tstart) * (2 * Cdim) + dir * Cdim + c;

    float num = 0.0f, den = 0.0f, mx = -1e38f;

    const int PF = 4;
    float rr[PF], kk[PF], vv[PF];
    #pragma unroll
    for (int i = 0; i < PF; ++i) {
        rr[i] = p[0]; kk[i] = p[Cdim]; vv[i] = p[2 * Cdim];
        p += tstep;
    }

    for (int t0 = 0; t0 < Tdim; t0 += PF) {
        float rn[PF], kn[PF], vn[PF];
        if (t0 + PF < Tdim) {
            #pragma unroll
            for (int i = 0; i < PF; ++i) {
                rn[i] = p[0]; kn[i] = p[Cdim]; vn[i] = p[2 * Cdim];
                p += tstep;
            }
        }
        #pragma unroll
        for (int i = 0; i < PF; ++i) {
            const float k_ = kk[i], v_ = vv[i], r_ = rr[i];
            // output with running-max stabilization
            const float ku = k_ + u;
            const float m  = fmaxf(mx, ku);
            const float e1 = __expf(mx - m);
            const float e2 = __expf(ku - m);
            const float y  = (e1 * num + e2 * v_) / (e1 * den + e2);
            const float sr = 1.0f / (1.0f + __expf(-r_));
            po[0] = sr * y;
            po += ostep;
            // state update
            const float mw  = mx + w;
            const float mn  = fmaxf(mw, k_);
            const float e1s = __expf(mw - mn);
            const float e2s = __expf(k_ - mn);
            num = e1s * num + e2s * v_;
            den = e1s * den + e2s;
            mx  = mn;
        }
        #pragma unroll
        for (int i = 0; i < PF; ++i) { rr[i] = rn[i]; kk[i] = kn[i]; vv[i] = vn[i]; }
    }
}

// ---------------------------------------------------------------------------
extern "C" void kernel_launch(void* const* d_in, const int* in_sizes, int n_in,
                              void* d_out, int out_size, void* d_ws, size_t ws_size,
                              hipStream_t stream)
{
    const float* x    = (const float*)d_in[0];   // [B,T,C]
    const float* rkvw = (const float*)d_in[1];   // [6C, C]
    const float* outw = (const float*)d_in[2];   // [C, 2C]
    const float* td   = (const float*)d_in[3];
    const float* tf   = (const float*)d_in[4];
    const float* tdr  = (const float*)d_in[5];
    const float* tfr  = (const float*)d_in[6];
    float* out = (float*)d_out;                  // [B,T,C]

    float* rkv    = (float*)d_ws;                               // [B*T, 6C]  192 MiB
    float* outcat = rkv + (size_t)Bdim * Tdim * 6 * Cdim;       // [B*T, 2C]   64 MiB

    const int M = Bdim * Tdim;   // 8192

    dim3 blk(256);

    // GEMM1: rkv[m,d] = sum_c x[m,c] * rkv_w[d,c]   (M=8192, N=6144, K=1024)
    dim3 g1((6 * Cdim) / BN, M / BM);
    hipLaunchKernelGGL(sgemm_nt, g1, blk, 0, stream, x, rkvw, rkv, M, 6 * Cdim, Cdim);

    // fused sigmoid + bidirectional WKV scan
    dim3 g2(Bdim * 2 * (Cdim / 256));
    hipLaunchKernelGGL(wkv_scan, g2, blk, 0, stream, rkv, td, tf, tdr, tfr, outcat);

    // GEMM2: out[m,c] = sum_d outcat[m,d] * out_w[c,d]   (M=8192, N=1024, K=2048)
    dim3 g3(Cdim / BN, M / BM);
    hipLaunchKernelGGL(sgemm_nt, g3, blk, 0, stream, outcat, outw, out, M, Cdim, 2 * Cdim);
}

// Round 2
// 634.548 us; speedup vs baseline: 3.1488x; 3.1488x over previous
//
#include <hip/hip_runtime.h>
#include <cstdint>
#include <cstddef>

#define Bdim 4
#define Tdim 2048
#define Cdim 1024

typedef __attribute__((ext_vector_type(8))) short bf16x8;
typedef __attribute__((ext_vector_type(4))) float f32x4;

// fp32 -> bf16, round-to-nearest-even (finite inputs)
__device__ __forceinline__ unsigned short f2bf(float f) {
    unsigned int u = __float_as_uint(f);
    u += 0x7fffu + ((u >> 16) & 1u);
    return (unsigned short)(u >> 16);
}

__device__ __forceinline__ void gload_lds16(const void* g, void* l) {
    __builtin_amdgcn_global_load_lds(
        (const __attribute__((address_space(1))) unsigned int*)g,
        (__attribute__((address_space(3))) unsigned int*)l,
        16, 0, 0);
}

// ---------------------------------------------------------------------------
// elementwise fp32 -> bf16 cast (vectorized: float4 in, ushort4 out)
// ---------------------------------------------------------------------------
__global__ __launch_bounds__(256) void cast_f32_bf16(
    const float* __restrict__ in, unsigned short* __restrict__ out, int n4)
{
    int i = blockIdx.x * 256 + threadIdx.x;
    if (i >= n4) return;
    float4 v = ((const float4*)in)[i];
    ushort4 o;
    o.x = f2bf(v.x); o.y = f2bf(v.y); o.z = f2bf(v.z); o.w = f2bf(v.w);
    ((ushort4*)out)[i] = o;
}

// ---------------------------------------------------------------------------
// bf16 MFMA GEMM, NT: C[m,n] = sum_k A[m*K+k]*B[n*K+k], fp32 out.
// m97 structure: 128x128 tile, BK=32, 4 waves (2x2), 16x16x32 MFMA,
// 4x4 fragments/wave, global_load_lds width=16 into linear LDS.
// Requires: M%128==0, N%128==0, K%32==0.
// ---------------------------------------------------------------------------
__global__ __launch_bounds__(256) void gemm_bf16_nt(
    const unsigned short* __restrict__ A, const unsigned short* __restrict__ B,
    float* __restrict__ C, int M, int N, int K)
{
    __shared__ unsigned short As[128 * 32];   // [row][k] row-major, 64B/row
    __shared__ unsigned short Bs[128 * 32];

    const int tid  = threadIdx.x;
    const int wave = tid >> 6;
    const int lane = tid & 63;
    const int m0 = blockIdx.y * 128;
    const int n0 = blockIdx.x * 128;
    const int wr = wave >> 1, wc = wave & 1;   // wave -> 64x64 output quadrant

    // staging: thread tid covers 16B at row tid/4, k-chunk (tid%4)*8
    const int srow = tid >> 2;                 // 0..63
    const int scol = (tid & 3) * 8;            // bf16 elems
    const unsigned short* Ag = A + (size_t)(m0 + srow) * K + scol;
    const unsigned short* Bg = B + (size_t)(n0 + srow) * K + scol;
    // wave-uniform LDS bases (lane l lands at +l*16 automatically)
    char* AsW = (char*)As + wave * 1024;
    char* BsW = (char*)Bs + wave * 1024;

    f32x4 acc[4][4] = {};

    const int fr = lane & 15;          // fragment row within 16
    const int fk = (lane >> 4) * 8;    // k-offset (8 bf16 per lane)

    for (int k0 = 0; k0 < K; k0 += 32) {
        // stage A,B tiles (rows 0-63 then 64-127)
        gload_lds16(Ag + k0,                  AsW);
        gload_lds16(Ag + k0 + (size_t)64 * K, AsW + 4096);
        gload_lds16(Bg + k0,                  BsW);
        gload_lds16(Bg + k0 + (size_t)64 * K, BsW + 4096);
        __syncthreads();   // drains vmcnt + barrier

        bf16x8 af[4], bfr_[4];
        #pragma unroll
        for (int f = 0; f < 4; ++f) {
            af[f]   = *(const bf16x8*)&As[(wr * 64 + f * 16 + fr) * 32 + fk];
            bfr_[f] = *(const bf16x8*)&Bs[(wc * 64 + f * 16 + fr) * 32 + fk];
        }
        #pragma unroll
        for (int i = 0; i < 4; ++i)
            #pragma unroll
            for (int j = 0; j < 4; ++j)
                acc[i][j] = __builtin_amdgcn_mfma_f32_16x16x32_bf16(
                    af[i], bfr_[j], acc[i][j], 0, 0, 0);
        __syncthreads();   // protect LDS before next stage
    }

    // C/D layout (m89-verified): col = lane&15, row = (lane>>4)*4 + reg
    #pragma unroll
    for (int i = 0; i < 4; ++i) {
        const int row = m0 + wr * 64 + i * 16 + (lane >> 4) * 4;
        #pragma unroll
        for (int j = 0; j < 4; ++j) {
            const int col = n0 + wc * 64 + j * 16 + (lane & 15);
            #pragma unroll
            for (int r = 0; r < 4; ++r)
                C[(size_t)(row + r) * N + col] = acc[i][j][r];
        }
    }
}

// ---------------------------------------------------------------------------
// Fused sigmoid(r) * WKV scan, both directions. fp32 in, bf16 out.
// rkv layout: [B, T, 2, 3, C]; out: out_cat [B, T, 2C] bf16.
// One thread per (b, dir, c). Depth-4 register prefetch over t.
// ---------------------------------------------------------------------------
__global__ __launch_bounds__(256) void wkv_scan(
    const float* __restrict__ rkv,
    const float* __restrict__ td,  const float* __restrict__ tf,
    const float* __restrict__ tdr, const float* __restrict__ tfr,
    unsigned short* __restrict__ outcat)
{
    const int tid = threadIdx.x;
    const int bi  = blockIdx.x;
    const int b   = bi >> 3;
    const int rem = bi & 7;
    const int dir = rem >> 2;
    const int c   = (rem & 3) * 256 + tid;

    const float w = -__expf(dir ? tdr[c] : td[c]);
    const float u = dir ? tfr[c] : tf[c];

    const int strideT = 6 * Cdim;
    const int tstart  = dir ? (Tdim - 1) : 0;
    const int tstep   = dir ? -strideT : strideT;
    const int ostep   = dir ? -(2 * Cdim) : (2 * Cdim);

    const float* p = rkv + ((size_t)b * Tdim + tstart) * strideT + dir * 3 * Cdim + c;
    unsigned short* po = outcat + ((size_t)b * Tdim + tstart) * (2 * Cdim) + dir * Cdim + c;

    float num = 0.0f, den = 0.0f, mx = -1e38f;

    const int PF = 4;
    float rr[PF], kk[PF], vv[PF];
    #pragma unroll
    for (int i = 0; i < PF; ++i) {
        rr[i] = p[0]; kk[i] = p[Cdim]; vv[i] = p[2 * Cdim];
        p += tstep;
    }

    for (int t0 = 0; t0 < Tdim; t0 += PF) {
        float rn[PF], kn[PF], vn[PF];
        if (t0 + PF < Tdim) {
            #pragma unroll
            for (int i = 0; i < PF; ++i) {
                rn[i] = p[0]; kn[i] = p[Cdim]; vn[i] = p[2 * Cdim];
                p += tstep;
            }
        }
        #pragma unroll
        for (int i = 0; i < PF; ++i) {
            const float k_ = kk[i], v_ = vv[i], r_ = rr[i];
            const float ku = k_ + u;
            const float m  = fmaxf(mx, ku);
            const float e1 = __expf(mx - m);
            const float e2 = __expf(ku - m);
            const float y  = (e1 * num + e2 * v_) / (e1 * den + e2);
            const float sr = 1.0f / (1.0f + __expf(-r_));
            *po = f2bf(sr * y);
            po += ostep;
            const float mw  = mx + w;
            const float mn  = fmaxf(mw, k_);
            const float e1s = __expf(mw - mn);
            const float e2s = __expf(k_ - mn);
            num = e1s * num + e2s * v_;
            den = e1s * den + e2s;
            mx  = mn;
        }
        #pragma unroll
        for (int i = 0; i < PF; ++i) { rr[i] = rn[i]; kk[i] = kn[i]; vv[i] = vn[i]; }
    }
}

// ---------------------------------------------------------------------------
extern "C" void kernel_launch(void* const* d_in, const int* in_sizes, int n_in,
                              void* d_out, int out_size, void* d_ws, size_t ws_size,
                              hipStream_t stream)
{
    const float* x    = (const float*)d_in[0];   // [B,T,C]
    const float* rkvw = (const float*)d_in[1];   // [6C, C]
    const float* outw = (const float*)d_in[2];   // [C, 2C]
    const float* td   = (const float*)d_in[3];
    const float* tf   = (const float*)d_in[4];
    const float* tdr  = (const float*)d_in[5];
    const float* tfr  = (const float*)d_in[6];
    float* out = (float*)d_out;                  // [B,T,C] fp32

    const int M = Bdim * Tdim;                   // 8192

    // workspace layout (exactly 256 MiB):
    char* ws = (char*)d_ws;
    float*          rkv = (float*)ws;                          // 192 MiB fp32 [B,T,6C]
    unsigned short* xb  = (unsigned short*)(ws + 201326592);   //  16 MiB bf16 x
    unsigned short* wb  = (unsigned short*)(ws + 218103808);   //  12 MiB bf16 rkv_w
    unsigned short* ob  = (unsigned short*)(ws + 230686720);   //   4 MiB bf16 out_w
    unsigned short* cat = (unsigned short*)(ws + 234881024);   //  32 MiB bf16 out_cat

    dim3 blk(256);

    // casts
    hipLaunchKernelGGL(cast_f32_bf16, dim3((M * Cdim / 4 + 255) / 256), blk, 0, stream,
                       x, xb, M * Cdim / 4);
    hipLaunchKernelGGL(cast_f32_bf16, dim3((6 * Cdim * Cdim / 4 + 255) / 256), blk, 0, stream,
                       rkvw, wb, 6 * Cdim * Cdim / 4);
    hipLaunchKernelGGL(cast_f32_bf16, dim3((Cdim * 2 * Cdim / 4 + 255) / 256), blk, 0, stream,
                       outw, ob, Cdim * 2 * Cdim / 4);

    // GEMM1: rkv[m,d] = sum_c x[m,c]*rkv_w[d,c]  (M=8192, N=6144, K=1024)
    hipLaunchKernelGGL(gemm_bf16_nt, dim3(6 * Cdim / 128, M / 128), blk, 0, stream,
                       xb, wb, rkv, M, 6 * Cdim, Cdim);

    // fused sigmoid + bidirectional WKV scan (fp32 state, bf16 out)
    hipLaunchKernelGGL(wkv_scan, dim3(Bdim * 2 * (Cdim / 256)), blk, 0, stream,
                       rkv, td, tf, tdr, tfr, cat);

    // GEMM2: out[m,c] = sum_d outcat[m,d]*out_w[c,d]  (M=8192, N=1024, K=2048)
    hipLaunchKernelGGL(gemm_bf16_nt, dim3(Cdim / 128, M / 128), blk, 0, stream,
                       cat, ob, out, M, Cdim, 2 * Cdim);
}

// Round 3
// 341.574 us; speedup vs baseline: 5.8496x; 1.8577x over previous
//
#include <hip/hip_runtime.h>
#include <cstdint>
#include <cstddef>

#define Bdim 4
#define Tdim 2048
#define Cdim 1024

#define SEG  16                  // segments per sequence
#define CHB  16                  // channels per block
#define LSEG (Tdim / SEG)        // 128 steps per segment

typedef __attribute__((ext_vector_type(8))) short bf16x8;
typedef __attribute__((ext_vector_type(4))) float f32x4;

// fp32 -> bf16, round-to-nearest-even (finite inputs)
__device__ __forceinline__ unsigned short f2bf(float f) {
    unsigned int u = __float_as_uint(f);
    u += 0x7fffu + ((u >> 16) & 1u);
    return (unsigned short)(u >> 16);
}

__device__ __forceinline__ void gload_lds16(const void* g, void* l) {
    __builtin_amdgcn_global_load_lds(
        (const __attribute__((address_space(1))) unsigned int*)g,
        (__attribute__((address_space(3))) unsigned int*)l,
        16, 0, 0);
}

// ---------------------------------------------------------------------------
// elementwise fp32 -> bf16 cast (vectorized: float4 in, ushort4 out)
// ---------------------------------------------------------------------------
__global__ __launch_bounds__(256) void cast_f32_bf16(
    const float* __restrict__ in, unsigned short* __restrict__ out, int n4)
{
    int i = blockIdx.x * 256 + threadIdx.x;
    if (i >= n4) return;
    float4 v = ((const float4*)in)[i];
    ushort4 o;
    o.x = f2bf(v.x); o.y = f2bf(v.y); o.z = f2bf(v.z); o.w = f2bf(v.w);
    ((ushort4*)out)[i] = o;
}

// ---------------------------------------------------------------------------
// bf16 MFMA GEMM, NT: C[m,n] = sum_k A[m*K+k]*B[n*K+k], fp32 out.
// m97 structure: 128x128 tile, BK=32, 4 waves (2x2), 16x16x32 MFMA.
// ---------------------------------------------------------------------------
__global__ __launch_bounds__(256) void gemm_bf16_nt(
    const unsigned short* __restrict__ A, const unsigned short* __restrict__ B,
    float* __restrict__ C, int M, int N, int K)
{
    __shared__ unsigned short As[128 * 32];
    __shared__ unsigned short Bs[128 * 32];

    const int tid  = threadIdx.x;
    const int wave = tid >> 6;
    const int lane = tid & 63;
    const int m0 = blockIdx.y * 128;
    const int n0 = blockIdx.x * 128;
    const int wr = wave >> 1, wc = wave & 1;

    const int srow = tid >> 2;
    const int scol = (tid & 3) * 8;
    const unsigned short* Ag = A + (size_t)(m0 + srow) * K + scol;
    const unsigned short* Bg = B + (size_t)(n0 + srow) * K + scol;
    char* AsW = (char*)As + wave * 1024;
    char* BsW = (char*)Bs + wave * 1024;

    f32x4 acc[4][4] = {};

    const int fr = lane & 15;
    const int fk = (lane >> 4) * 8;

    for (int k0 = 0; k0 < K; k0 += 32) {
        gload_lds16(Ag + k0,                  AsW);
        gload_lds16(Ag + k0 + (size_t)64 * K, AsW + 4096);
        gload_lds16(Bg + k0,                  BsW);
        gload_lds16(Bg + k0 + (size_t)64 * K, BsW + 4096);
        __syncthreads();

        bf16x8 af[4], bfr_[4];
        #pragma unroll
        for (int f = 0; f < 4; ++f) {
            af[f]   = *(const bf16x8*)&As[(wr * 64 + f * 16 + fr) * 32 + fk];
            bfr_[f] = *(const bf16x8*)&Bs[(wc * 64 + f * 16 + fr) * 32 + fk];
        }
        #pragma unroll
        for (int i = 0; i < 4; ++i)
            #pragma unroll
            for (int j = 0; j < 4; ++j)
                acc[i][j] = __builtin_amdgcn_mfma_f32_16x16x32_bf16(
                    af[i], bfr_[j], acc[i][j], 0, 0, 0);
        __syncthreads();
    }

    #pragma unroll
    for (int i = 0; i < 4; ++i) {
        const int row = m0 + wr * 64 + i * 16 + (lane >> 4) * 4;
        #pragma unroll
        for (int j = 0; j < 4; ++j) {
            const int col = n0 + wc * 64 + j * 16 + (lane & 15);
            #pragma unroll
            for (int r = 0; r < 4; ++r)
                C[(size_t)(row + r) * N + col] = acc[i][j][r];
        }
    }
}

// ---------------------------------------------------------------------------
// Segmented-parallel fused sigmoid(r)*WKV scan, both directions.
// rkv layout: [B, T, 2, 3, C] fp32; out: out_cat [B, T, 2C] bf16.
// Block = 256 thr = CHB(16) channels x SEG(16) segments of L=128.
// 3 phases: segment summaries -> in-block exclusive combine -> replay+emit.
// State (num,den,mx) == (N,D) = (num,den)*e^mx; segment map is affine:
//   N_out = e^{w*L}*N_in + Bn  (Bn from zero-state local run).
// ---------------------------------------------------------------------------
__global__ __launch_bounds__(256) void wkv_scan_par(
    const float* __restrict__ rkv,
    const float* __restrict__ td,  const float* __restrict__ tf,
    const float* __restrict__ tdr, const float* __restrict__ tfr,
    unsigned short* __restrict__ outcat)
{
    __shared__ float sBn[SEG][CHB], sBd[SEG][CHB], sMb[SEG][CHB];

    const int tid = threadIdx.x;
    const int ch  = tid & (CHB - 1);
    const int seg = tid >> 4;

    const int bi  = blockIdx.x;          // b(4) x dir(2) x cgroup(64)
    const int b   = bi >> 7;
    const int rem = bi & 127;
    const int dir = rem >> 6;
    const int c   = (rem & 63) * CHB + ch;

    const float w = -__expf(dir ? tdr[c] : td[c]);
    const float u = dir ? tfr[c] : tf[c];

    const int strideT = 6 * Cdim;
    const int tstep   = dir ? -strideT : strideT;
    const int t0      = dir ? (Tdim - 1 - seg * LSEG) : (seg * LSEG);

    const float* pbase = rkv + ((size_t)b * Tdim + t0) * strideT + dir * 3 * Cdim + c;

    const int PF = 4;

    // ---- phase 1: segment-local summary (k,v only) ----
    float bn = 0.0f, bd = 0.0f, mb = -1e38f;
    {
        const float* q = pbase;
        float kk[PF], vv[PF];
        #pragma unroll
        for (int i = 0; i < PF; ++i) { kk[i] = q[Cdim]; vv[i] = q[2 * Cdim]; q += tstep; }
        for (int t = 0; t < LSEG; t += PF) {
            float kn[PF], vn[PF];
            if (t + PF < LSEG) {
                #pragma unroll
                for (int i = 0; i < PF; ++i) { kn[i] = q[Cdim]; vn[i] = q[2 * Cdim]; q += tstep; }
            }
            #pragma unroll
            for (int i = 0; i < PF; ++i) {
                const float k_ = kk[i], v_ = vv[i];
                const float mw = mb + w;
                const float mn = fmaxf(mw, k_);
                const float e1 = __expf(mw - mn);
                const float e2 = __expf(k_ - mn);
                bn = e1 * bn + e2 * v_;
                bd = e1 * bd + e2;
                mb = mn;
            }
            #pragma unroll
            for (int i = 0; i < PF; ++i) { kk[i] = kn[i]; vv[i] = vn[i]; }
        }
    }
    sBn[seg][ch] = bn; sBd[seg][ch] = bd; sMb[seg][ch] = mb;
    __syncthreads();

    // ---- phase 2: exclusive combine over segments (16 lanes active) ----
    if (tid < CHB) {
        float n = 0.0f, d = 0.0f, m = -1e38f;
        const float a = w * (float)LSEG;
        for (int s = 0; s < SEG; ++s) {
            const float tn = sBn[s][tid], tdn = sBd[s][tid], tm = sMb[s][tid];
            sBn[s][tid] = n; sBd[s][tid] = d; sMb[s][tid] = m;
            const float ma = m + a;
            const float mm = fmaxf(ma, tm);
            const float e1 = __expf(ma - mm);
            const float e2 = __expf(tm - mm);
            n = e1 * n + e2 * tn;
            d = e1 * d + e2 * tdn;
            m = mm;
        }
    }
    __syncthreads();

    // ---- phase 3: replay segment from prefix, emit outputs ----
    float num = sBn[seg][ch], den = sBd[seg][ch], mx = sMb[seg][ch];
    {
        const float* q = pbase;
        unsigned short* po = outcat + ((size_t)b * Tdim + t0) * (2 * Cdim) + dir * Cdim + c;
        const int ostep = dir ? -(2 * Cdim) : (2 * Cdim);

        float rr[PF], kk[PF], vv[PF];
        #pragma unroll
        for (int i = 0; i < PF; ++i) {
            rr[i] = q[0]; kk[i] = q[Cdim]; vv[i] = q[2 * Cdim]; q += tstep;
        }
        for (int t = 0; t < LSEG; t += PF) {
            float rn[PF], kn[PF], vn[PF];
            if (t + PF < LSEG) {
                #pragma unroll
                for (int i = 0; i < PF; ++i) {
                    rn[i] = q[0]; kn[i] = q[Cdim]; vn[i] = q[2 * Cdim]; q += tstep;
                }
            }
            #pragma unroll
            for (int i = 0; i < PF; ++i) {
                const float k_ = kk[i], v_ = vv[i], r_ = rr[i];
                const float ku = k_ + u;
                const float m  = fmaxf(mx, ku);
                const float e1 = __expf(mx - m);
                const float e2 = __expf(ku - m);
                const float y  = (e1 * num + e2 * v_) / (e1 * den + e2);
                const float sr = 1.0f / (1.0f + __expf(-r_));
                *po = f2bf(sr * y);
                po += ostep;
                const float mw  = mx + w;
                const float mn  = fmaxf(mw, k_);
                const float e1s = __expf(mw - mn);
                const float e2s = __expf(k_ - mn);
                num = e1s * num + e2s * v_;
                den = e1s * den + e2s;
                mx  = mn;
            }
            #pragma unroll
            for (int i = 0; i < PF; ++i) { rr[i] = rn[i]; kk[i] = kn[i]; vv[i] = vn[i]; }
        }
    }
}

// ---------------------------------------------------------------------------
extern "C" void kernel_launch(void* const* d_in, const int* in_sizes, int n_in,
                              void* d_out, int out_size, void* d_ws, size_t ws_size,
                              hipStream_t stream)
{
    const float* x    = (const float*)d_in[0];
    const float* rkvw = (const float*)d_in[1];
    const float* outw = (const float*)d_in[2];
    const float* td   = (const float*)d_in[3];
    const float* tf   = (const float*)d_in[4];
    const float* tdr  = (const float*)d_in[5];
    const float* tfr  = (const float*)d_in[6];
    float* out = (float*)d_out;

    const int M = Bdim * Tdim;   // 8192

    char* ws = (char*)d_ws;
    float*          rkv = (float*)ws;                          // 192 MiB fp32 [B,T,6C]
    unsigned short* xb  = (unsigned short*)(ws + 201326592);   //  16 MiB bf16 x
    unsigned short* wb  = (unsigned short*)(ws + 218103808);   //  12 MiB bf16 rkv_w
    unsigned short* ob  = (unsigned short*)(ws + 230686720);   //   4 MiB bf16 out_w
    unsigned short* cat = (unsigned short*)(ws + 234881024);   //  32 MiB bf16 out_cat

    dim3 blk(256);

    hipLaunchKernelGGL(cast_f32_bf16, dim3((M * Cdim / 4 + 255) / 256), blk, 0, stream,
                       x, xb, M * Cdim / 4);
    hipLaunchKernelGGL(cast_f32_bf16, dim3((6 * Cdim * Cdim / 4 + 255) / 256), blk, 0, stream,
                       rkvw, wb, 6 * Cdim * Cdim / 4);
    hipLaunchKernelGGL(cast_f32_bf16, dim3((Cdim * 2 * Cdim / 4 + 255) / 256), blk, 0, stream,
                       outw, ob, Cdim * 2 * Cdim / 4);

    // GEMM1: rkv[m,d] = sum_c x[m,c]*rkv_w[d,c]  (M=8192, N=6144, K=1024)
    hipLaunchKernelGGL(gemm_bf16_nt, dim3(6 * Cdim / 128, M / 128), blk, 0, stream,
                       xb, wb, rkv, M, 6 * Cdim, Cdim);

    // segmented-parallel fused sigmoid + bidirectional WKV scan
    hipLaunchKernelGGL(wkv_scan_par, dim3(Bdim * 2 * (Cdim / CHB)), blk, 0, stream,
                       rkv, td, tf, tdr, tfr, cat);

    // GEMM2: out[m,c] = sum_d outcat[m,d]*out_w[c,d]  (M=8192, N=1024, K=2048)
    hipLaunchKernelGGL(gemm_bf16_nt, dim3(Cdim / 128, M / 128), blk, 0, stream,
                       cat, ob, out, M, Cdim, 2 * Cdim);
}

// Round 4
// 307.751 us; speedup vs baseline: 6.4925x; 1.1099x over previous
//
#include <hip/hip_runtime.h>
#include <cstdint>
#include <cstddef>

#define Bdim 4
#define Tdim 2048
#define Cdim 1024

#define SEG  16
#define CHB  16
#define LSEG (Tdim / SEG)

typedef __attribute__((ext_vector_type(8))) short bf16x8;
typedef __attribute__((ext_vector_type(4))) float f32x4;

__device__ __forceinline__ unsigned short f2bf(float f) {
    unsigned int u = __float_as_uint(f);
    u += 0x7fffu + ((u >> 16) & 1u);
    return (unsigned short)(u >> 16);
}

__device__ __forceinline__ void gload_lds16(const void* g, void* l) {
    __builtin_amdgcn_global_load_lds(
        (const __attribute__((address_space(1))) unsigned int*)g,
        (__attribute__((address_space(3))) unsigned int*)l,
        16, 0, 0);
}

// ---------------------------------------------------------------------------
// elementwise fp32 -> bf16 cast
// ---------------------------------------------------------------------------
__global__ __launch_bounds__(256) void cast_f32_bf16(
    const float* __restrict__ in, unsigned short* __restrict__ out, int n4)
{
    int i = blockIdx.x * 256 + threadIdx.x;
    if (i >= n4) return;
    float4 v = ((const float4*)in)[i];
    ushort4 o;
    o.x = f2bf(v.x); o.y = f2bf(v.y); o.z = f2bf(v.z); o.w = f2bf(v.w);
    ((ushort4*)out)[i] = o;
}

// ---------------------------------------------------------------------------
// 256x256 8-phase bf16 MFMA GEMM (NT): C[m,n] = sum_k A[m*K+k]*B[n*K+k].
// 512 thr = 8 waves (WARPS_M=2 x WARPS_N=4); per-wave output 128x64.
// BK=64 split in two 32-k halves; LDS slots: {A,B} x {t0,t1} x {k0,k1},
// each [256 rows][32 bf16] = 16 KiB, total 128 KiB.
//
// Steady-state iteration i (t0 slots hold ktile 2i, t1 hold 2i+1):
//   P1 (t0,k0,mh0) stage A(2i+1)k1->A[1][1]      (slot freed: prev P8 barrier)
//   P2 (t0,k0,mh1) stage B(2i+1)k1->B[1][1] vm(8)
//   P3 (t0,k1,mh0) stage A(2i+2)k0->A[0][0]      (freed after P2)
//   P4 (t0,k1,mh1) stage B(2i+2)k0->B[0][0] vm(8)
//   P5 (t1,k0,mh0) stage A(2i+2)k1->A[0][1]      (freed after P4)
//   P6 (t1,k0,mh1) stage B(2i+2)k1->B[0][1] vm(8)
//   P7 (t1,k1,mh0) stage A(2i+3)k0->A[1][0]      (freed after P6)
//   P8 (t1,k1,mh1) stage B(2i+3)k0->B[1][0] vm(8)
// Every read's data: staged 6 phases earlier, vmcnt(8)-confirmed >=2 phases
// earlier, barrier after the vmcnt -> all waves' stages arrived. vmcnt never
// drains below 8 outstanding (T4). Stage->read slot reuse protected by the
// end-of-phase barrier after all lgkm-completed reads.
//
// Swizzle (T2): logical (row, 16B-chunk s) stored at chunk c = s ^ ((row>>1)&3).
// gload_lds dest is linear => pre-swizzle global source per-lane:
//   lane l covers row g*16+(l>>2), logical chunk (l&3)^((l>>3)&3).
// ds_read byte = row*64 + ((lane>>4) ^ ((fr>>1)&3))*16  -> conflict-free.
// ---------------------------------------------------------------------------
__device__ __forceinline__ void stage_half(
    const unsigned short* __restrict__ G, int row0, int K, int elemoff,
    char* slot, int wave, int lane)
{
    const int sl = (lane & 3) ^ ((lane >> 3) & 3);
    const unsigned short* gp = G + (size_t)(row0 + wave * 16 + (lane >> 2)) * K
                                 + elemoff + sl * 8;
    gload_lds16(gp, slot + wave * 1024);
    gload_lds16(gp + (size_t)128 * K, slot + 8192 + wave * 1024);
}

#define GPHASE(D, KH, MH, SG, SROW0, SOFF, SSLOT, VM)                          \
  {                                                                            \
    const char* As_ = ldsb + (D)*32768 + (KH)*16384;                           \
    const char* Bs_ = ldsb + 65536 + (D)*32768 + (KH)*16384;                   \
    bf16x8 a_[4], b_[4];                                                       \
    _Pragma("unroll")                                                          \
    for (int i_ = 0; i_ < 4; ++i_)                                             \
      a_[i_] = *(const bf16x8*)(As_ + (wm*128 + ((MH)*4+i_)*16 + fr)*64 + cswz);\
    _Pragma("unroll")                                                          \
    for (int j_ = 0; j_ < 4; ++j_)                                             \
      b_[j_] = *(const bf16x8*)(Bs_ + (wn*64 + j_*16 + fr)*64 + cswz);         \
    stage_half(SG, SROW0, K, SOFF, SSLOT, wave, lane);                         \
    __builtin_amdgcn_s_barrier();                                              \
    __builtin_amdgcn_sched_barrier(0);                                         \
    __builtin_amdgcn_s_setprio(1);                                             \
    _Pragma("unroll")                                                          \
    for (int i_ = 0; i_ < 4; ++i_)                                             \
      _Pragma("unroll")                                                        \
      for (int j_ = 0; j_ < 4; ++j_)                                           \
        acc[(MH)*4+i_][j_] = __builtin_amdgcn_mfma_f32_16x16x32_bf16(          \
            a_[i_], b_[j_], acc[(MH)*4+i_][j_], 0, 0, 0);                      \
    __builtin_amdgcn_s_setprio(0);                                             \
    if (VM) { asm volatile("s_waitcnt vmcnt(8)" ::: "memory"); }               \
    __builtin_amdgcn_s_barrier();                                              \
    __builtin_amdgcn_sched_barrier(0);                                         \
  }

__global__ __launch_bounds__(512, 2) void gemm_bf16_nt_256(
    const unsigned short* __restrict__ A, const unsigned short* __restrict__ B,
    float* __restrict__ C, int M, int N, int K, int gx)
{
    __shared__ char ldsbuf[131072];
    char* ldsb = ldsbuf;

    const int tid  = threadIdx.x;
    const int wave = tid >> 6;
    const int lane = tid & 63;
    const int wm = wave >> 2;          // 0..1  (M direction, 128 rows each)
    const int wn = wave & 3;           // 0..3  (N direction, 64 cols each)
    const int fr = lane & 15;
    const int cswz = (((lane >> 4) ^ ((fr >> 1) & 3)) << 4);

    // XCD-aware block swizzle (grid % 8 == 0 guaranteed by caller)
    const int nwg = gridDim.x;
    const int cpx = nwg >> 3;
    const int b0  = blockIdx.x;
    const int swz = (b0 & 7) * cpx + (b0 >> 3);
    const int bx  = swz % gx;
    const int by  = swz / gx;
    const int m0 = by * 256;
    const int n0 = bx * 256;

    const int NKT = K >> 6;            // 64-wide K-tiles
    const int NI  = K >> 7;            // iterations (2 K-tiles each)

    f32x4 acc[8][4] = {};

    // prologue: seed t0 (ktile 0) fully + t1 (ktile 1) k0
    stage_half(A, m0, K, 0,  ldsb + 0,             wave, lane);  // A[0][0]
    stage_half(B, n0, K, 0,  ldsb + 65536,         wave, lane);  // B[0][0]
    stage_half(A, m0, K, 32, ldsb + 16384,         wave, lane);  // A[0][1]
    stage_half(B, n0, K, 32, ldsb + 65536 + 16384, wave, lane);  // B[0][1]
    stage_half(A, m0, K, 64, ldsb + 32768,         wave, lane);  // A[1][0]
    stage_half(B, n0, K, 64, ldsb + 65536 + 32768, wave, lane);  // B[1][0]
    asm volatile("s_waitcnt vmcnt(8)" ::: "memory");   // A[0][0],B[0][0] arrived
    __builtin_amdgcn_s_barrier();
    __builtin_amdgcn_sched_barrier(0);

    for (int i = 0; i < NI; ++i) {
        const int k1e = (2 * i + 1) * 64;
        int k2 = 2 * i + 2; if (k2 >= NKT) k2 = NKT - 1;
        int k3 = 2 * i + 3; if (k3 >= NKT) k3 = NKT - 1;
        const int k2e = k2 * 64, k3e = k3 * 64;

        GPHASE(0, 0, 0, A, m0, k1e + 32, ldsb + 32768 + 16384,         0)  // P1
        GPHASE(0, 0, 1, B, n0, k1e + 32, ldsb + 65536 + 32768 + 16384, 1)  // P2
        GPHASE(0, 1, 0, A, m0, k2e,      ldsb + 0,                     0)  // P3
        GPHASE(0, 1, 1, B, n0, k2e,      ldsb + 65536,                 1)  // P4
        GPHASE(1, 0, 0, A, m0, k2e + 32, ldsb + 16384,                 0)  // P5
        GPHASE(1, 0, 1, B, n0, k2e + 32, ldsb + 65536 + 16384,         1)  // P6
        GPHASE(1, 1, 0, A, m0, k3e,      ldsb + 32768,                 0)  // P7
        GPHASE(1, 1, 1, B, n0, k3e,      ldsb + 65536 + 32768,         1)  // P8
    }

    // epilogue: C/D layout col = lane&15, row = (lane>>4)*4 + reg
    #pragma unroll
    for (int mi = 0; mi < 8; ++mi) {
        const int row = m0 + wm * 128 + mi * 16 + (lane >> 4) * 4;
        #pragma unroll
        for (int nj = 0; nj < 4; ++nj) {
            const int col = n0 + wn * 64 + nj * 16 + fr;
            #pragma unroll
            for (int r = 0; r < 4; ++r)
                C[(size_t)(row + r) * N + col] = acc[mi][nj][r];
        }
    }
}

// ---------------------------------------------------------------------------
// Segmented-parallel fused sigmoid(r)*WKV scan (unchanged from R3).
// ---------------------------------------------------------------------------
__global__ __launch_bounds__(256) void wkv_scan_par(
    const float* __restrict__ rkv,
    const float* __restrict__ td,  const float* __restrict__ tf,
    const float* __restrict__ tdr, const float* __restrict__ tfr,
    unsigned short* __restrict__ outcat)
{
    __shared__ float sBn[SEG][CHB], sBd[SEG][CHB], sMb[SEG][CHB];

    const int tid = threadIdx.x;
    const int ch  = tid & (CHB - 1);
    const int seg = tid >> 4;

    const int bi  = blockIdx.x;
    const int b   = bi >> 7;
    const int rem = bi & 127;
    const int dir = rem >> 6;
    const int c   = (rem & 63) * CHB + ch;

    const float w = -__expf(dir ? tdr[c] : td[c]);
    const float u = dir ? tfr[c] : tf[c];

    const int strideT = 6 * Cdim;
    const int tstep   = dir ? -strideT : strideT;
    const int t0      = dir ? (Tdim - 1 - seg * LSEG) : (seg * LSEG);

    const float* pbase = rkv + ((size_t)b * Tdim + t0) * strideT + dir * 3 * Cdim + c;

    const int PF = 4;

    float bn = 0.0f, bd = 0.0f, mb = -1e38f;
    {
        const float* q = pbase;
        float kk[PF], vv[PF];
        #pragma unroll
        for (int i = 0; i < PF; ++i) { kk[i] = q[Cdim]; vv[i] = q[2 * Cdim]; q += tstep; }
        for (int t = 0; t < LSEG; t += PF) {
            float kn[PF], vn[PF];
            if (t + PF < LSEG) {
                #pragma unroll
                for (int i = 0; i < PF; ++i) { kn[i] = q[Cdim]; vn[i] = q[2 * Cdim]; q += tstep; }
            }
            #pragma unroll
            for (int i = 0; i < PF; ++i) {
                const float k_ = kk[i], v_ = vv[i];
                const float mw = mb + w;
                const float mn = fmaxf(mw, k_);
                const float e1 = __expf(mw - mn);
                const float e2 = __expf(k_ - mn);
                bn = e1 * bn + e2 * v_;
                bd = e1 * bd + e2;
                mb = mn;
            }
            #pragma unroll
            for (int i = 0; i < PF; ++i) { kk[i] = kn[i]; vv[i] = vn[i]; }
        }
    }
    sBn[seg][ch] = bn; sBd[seg][ch] = bd; sMb[seg][ch] = mb;
    __syncthreads();

    if (tid < CHB) {
        float n = 0.0f, d = 0.0f, m = -1e38f;
        const float a = w * (float)LSEG;
        for (int s = 0; s < SEG; ++s) {
            const float tn = sBn[s][tid], tdn = sBd[s][tid], tm = sMb[s][tid];
            sBn[s][tid] = n; sBd[s][tid] = d; sMb[s][tid] = m;
            const float ma = m + a;
            const float mm = fmaxf(ma, tm);
            const float e1 = __expf(ma - mm);
            const float e2 = __expf(tm - mm);
            n = e1 * n + e2 * tn;
            d = e1 * d + e2 * tdn;
            m = mm;
        }
    }
    __syncthreads();

    float num = sBn[seg][ch], den = sBd[seg][ch], mx = sMb[seg][ch];
    {
        const float* q = pbase;
        unsigned short* po = outcat + ((size_t)b * Tdim + t0) * (2 * Cdim) + dir * Cdim + c;
        const int ostep = dir ? -(2 * Cdim) : (2 * Cdim);

        float rr[PF], kk[PF], vv[PF];
        #pragma unroll
        for (int i = 0; i < PF; ++i) {
            rr[i] = q[0]; kk[i] = q[Cdim]; vv[i] = q[2 * Cdim]; q += tstep;
        }
        for (int t = 0; t < LSEG; t += PF) {
            float rn[PF], kn[PF], vn[PF];
            if (t + PF < LSEG) {
                #pragma unroll
                for (int i = 0; i < PF; ++i) {
                    rn[i] = q[0]; kn[i] = q[Cdim]; vn[i] = q[2 * Cdim]; q += tstep;
                }
            }
            #pragma unroll
            for (int i = 0; i < PF; ++i) {
                const float k_ = kk[i], v_ = vv[i], r_ = rr[i];
                const float ku = k_ + u;
                const float m  = fmaxf(mx, ku);
                const float e1 = __expf(mx - m);
                const float e2 = __expf(ku - m);
                const float y  = (e1 * num + e2 * v_) / (e1 * den + e2);
                const float sr = 1.0f / (1.0f + __expf(-r_));
                *po = f2bf(sr * y);
                po += ostep;
                const float mw  = mx + w;
                const float mn  = fmaxf(mw, k_);
                const float e1s = __expf(mw - mn);
                const float e2s = __expf(k_ - mn);
                num = e1s * num + e2s * v_;
                den = e1s * den + e2s;
                mx  = mn;
            }
            #pragma unroll
            for (int i = 0; i < PF; ++i) { rr[i] = rn[i]; kk[i] = kn[i]; vv[i] = vn[i]; }
        }
    }
}

// ---------------------------------------------------------------------------
extern "C" void kernel_launch(void* const* d_in, const int* in_sizes, int n_in,
                              void* d_out, int out_size, void* d_ws, size_t ws_size,
                              hipStream_t stream)
{
    const float* x    = (const float*)d_in[0];
    const float* rkvw = (const float*)d_in[1];
    const float* outw = (const float*)d_in[2];
    const float* td   = (const float*)d_in[3];
    const float* tf   = (const float*)d_in[4];
    const float* tdr  = (const float*)d_in[5];
    const float* tfr  = (const float*)d_in[6];
    float* out = (float*)d_out;

    const int M = Bdim * Tdim;   // 8192

    char* ws = (char*)d_ws;
    float*          rkv = (float*)ws;                          // 192 MiB fp32 [B,T,6C]
    unsigned short* xb  = (unsigned short*)(ws + 201326592);   //  16 MiB bf16 x
    unsigned short* wb  = (unsigned short*)(ws + 218103808);   //  12 MiB bf16 rkv_w
    unsigned short* ob  = (unsigned short*)(ws + 230686720);   //   4 MiB bf16 out_w
    unsigned short* cat = (unsigned short*)(ws + 234881024);   //  32 MiB bf16 out_cat

    dim3 blk(256);

    hipLaunchKernelGGL(cast_f32_bf16, dim3((M * Cdim / 4 + 255) / 256), blk, 0, stream,
                       x, xb, M * Cdim / 4);
    hipLaunchKernelGGL(cast_f32_bf16, dim3((6 * Cdim * Cdim / 4 + 255) / 256), blk, 0, stream,
                       rkvw, wb, 6 * Cdim * Cdim / 4);
    hipLaunchKernelGGL(cast_f32_bf16, dim3((Cdim * 2 * Cdim / 4 + 255) / 256), blk, 0, stream,
                       outw, ob, Cdim * 2 * Cdim / 4);

    // GEMM1: M=8192, N=6144, K=1024 -> grid 24*32 = 768 (%8==0)
    hipLaunchKernelGGL(gemm_bf16_nt_256, dim3((6 * Cdim / 256) * (M / 256)), dim3(512),
                       0, stream, xb, wb, rkv, M, 6 * Cdim, Cdim, 6 * Cdim / 256);

    hipLaunchKernelGGL(wkv_scan_par, dim3(Bdim * 2 * (Cdim / CHB)), blk, 0, stream,
                       rkv, td, tf, tdr, tfr, cat);

    // GEMM2: M=8192, N=1024, K=2048 -> grid 4*32 = 128 (%8==0)
    hipLaunchKernelGGL(gemm_bf16_nt_256, dim3((Cdim / 256) * (M / 256)), dim3(512),
                       0, stream, cat, ob, out, M, Cdim, 2 * Cdim, Cdim / 256);
}

// Round 5
// 259.249 us; speedup vs baseline: 7.7072x; 1.1871x over previous
//
#include <hip/hip_runtime.h>
#include <cstdint>
#include <cstddef>

#define Bdim 4
#define Tdim 2048
#define Cdim 1024

#define SEG  16
#define CHB  32
#define LSEG (Tdim / SEG)

typedef __attribute__((ext_vector_type(8))) short bf16x8;
typedef __attribute__((ext_vector_type(4))) float f32x4;

__device__ __forceinline__ unsigned short f2bf(float f) {
    unsigned int u = __float_as_uint(f);
    u += 0x7fffu + ((u >> 16) & 1u);
    return (unsigned short)(u >> 16);
}
__device__ __forceinline__ float bf2f(unsigned short h) {
    return __uint_as_float((unsigned int)h << 16);
}

__device__ __forceinline__ void gload_lds16(const void* g, void* l) {
    __builtin_amdgcn_global_load_lds(
        (const __attribute__((address_space(1))) unsigned int*)g,
        (__attribute__((address_space(3))) unsigned int*)l,
        16, 0, 0);
}

// ---------------------------------------------------------------------------
// elementwise fp32 -> bf16 cast
// ---------------------------------------------------------------------------
__global__ __launch_bounds__(256) void cast_f32_bf16(
    const float* __restrict__ in, unsigned short* __restrict__ out, int n4)
{
    int i = blockIdx.x * 256 + threadIdx.x;
    if (i >= n4) return;
    float4 v = ((const float4*)in)[i];
    ushort4 o;
    o.x = f2bf(v.x); o.y = f2bf(v.y); o.z = f2bf(v.z); o.w = f2bf(v.w);
    ((ushort4*)out)[i] = o;
}

// ---------------------------------------------------------------------------
// 256x256 8-phase bf16 MFMA GEMM (NT), bf16 OUTPUT. Schedule identical to R4
// (verified): counted vmcnt(8), st-swizzled LDS, XCD block swizzle.
// ---------------------------------------------------------------------------
__device__ __forceinline__ void stage_half(
    const unsigned short* __restrict__ G, int row0, int K, int elemoff,
    char* slot, int wave, int lane)
{
    const int sl = (lane & 3) ^ ((lane >> 3) & 3);
    const unsigned short* gp = G + (size_t)(row0 + wave * 16 + (lane >> 2)) * K
                                 + elemoff + sl * 8;
    gload_lds16(gp, slot + wave * 1024);
    gload_lds16(gp + (size_t)128 * K, slot + 8192 + wave * 1024);
}

#define GPHASE(D, KH, MH, SG, SROW0, SOFF, SSLOT, VM)                          \
  {                                                                            \
    const char* As_ = ldsb + (D)*32768 + (KH)*16384;                           \
    const char* Bs_ = ldsb + 65536 + (D)*32768 + (KH)*16384;                   \
    bf16x8 a_[4], b_[4];                                                       \
    _Pragma("unroll")                                                          \
    for (int i_ = 0; i_ < 4; ++i_)                                             \
      a_[i_] = *(const bf16x8*)(As_ + (wm*128 + ((MH)*4+i_)*16 + fr)*64 + cswz);\
    _Pragma("unroll")                                                          \
    for (int j_ = 0; j_ < 4; ++j_)                                             \
      b_[j_] = *(const bf16x8*)(Bs_ + (wn*64 + j_*16 + fr)*64 + cswz);         \
    stage_half(SG, SROW0, K, SOFF, SSLOT, wave, lane);                         \
    __builtin_amdgcn_s_barrier();                                              \
    __builtin_amdgcn_sched_barrier(0);                                         \
    __builtin_amdgcn_s_setprio(1);                                             \
    _Pragma("unroll")                                                          \
    for (int i_ = 0; i_ < 4; ++i_)                                             \
      _Pragma("unroll")                                                        \
      for (int j_ = 0; j_ < 4; ++j_)                                           \
        acc[(MH)*4+i_][j_] = __builtin_amdgcn_mfma_f32_16x16x32_bf16(          \
            a_[i_], b_[j_], acc[(MH)*4+i_][j_], 0, 0, 0);                      \
    __builtin_amdgcn_s_setprio(0);                                             \
    if (VM) { asm volatile("s_waitcnt vmcnt(8)" ::: "memory"); }               \
    __builtin_amdgcn_s_barrier();                                              \
    __builtin_amdgcn_sched_barrier(0);                                         \
  }

__global__ __launch_bounds__(512, 2) void gemm_bf16_nt_256_obf(
    const unsigned short* __restrict__ A, const unsigned short* __restrict__ B,
    unsigned short* __restrict__ C, int M, int N, int K, int gx)
{
    __shared__ char ldsbuf[131072];
    char* ldsb = ldsbuf;

    const int tid  = threadIdx.x;
    const int wave = tid >> 6;
    const int lane = tid & 63;
    const int wm = wave >> 2;
    const int wn = wave & 3;
    const int fr = lane & 15;
    const int cswz = (((lane >> 4) ^ ((fr >> 1) & 3)) << 4);

    const int nwg = gridDim.x;
    const int cpx = nwg >> 3;
    const int b0  = blockIdx.x;
    const int swz = (b0 & 7) * cpx + (b0 >> 3);
    const int bx  = swz % gx;
    const int by  = swz / gx;
    const int m0 = by * 256;
    const int n0 = bx * 256;

    const int NKT = K >> 6;
    const int NI  = K >> 7;

    f32x4 acc[8][4] = {};

    stage_half(A, m0, K, 0,  ldsb + 0,             wave, lane);
    stage_half(B, n0, K, 0,  ldsb + 65536,         wave, lane);
    stage_half(A, m0, K, 32, ldsb + 16384,         wave, lane);
    stage_half(B, n0, K, 32, ldsb + 65536 + 16384, wave, lane);
    stage_half(A, m0, K, 64, ldsb + 32768,         wave, lane);
    stage_half(B, n0, K, 64, ldsb + 65536 + 32768, wave, lane);
    asm volatile("s_waitcnt vmcnt(8)" ::: "memory");
    __builtin_amdgcn_s_barrier();
    __builtin_amdgcn_sched_barrier(0);

    for (int i = 0; i < NI; ++i) {
        const int k1e = (2 * i + 1) * 64;
        int k2 = 2 * i + 2; if (k2 >= NKT) k2 = NKT - 1;
        int k3 = 2 * i + 3; if (k3 >= NKT) k3 = NKT - 1;
        const int k2e = k2 * 64, k3e = k3 * 64;

        GPHASE(0, 0, 0, A, m0, k1e + 32, ldsb + 32768 + 16384,         0)
        GPHASE(0, 0, 1, B, n0, k1e + 32, ldsb + 65536 + 32768 + 16384, 1)
        GPHASE(0, 1, 0, A, m0, k2e,      ldsb + 0,                     0)
        GPHASE(0, 1, 1, B, n0, k2e,      ldsb + 65536,                 1)
        GPHASE(1, 0, 0, A, m0, k2e + 32, ldsb + 16384,                 0)
        GPHASE(1, 0, 1, B, n0, k2e + 32, ldsb + 65536 + 16384,         1)
        GPHASE(1, 1, 0, A, m0, k3e,      ldsb + 32768,                 0)
        GPHASE(1, 1, 1, B, n0, k3e,      ldsb + 65536 + 32768,         1)
    }

    #pragma unroll
    for (int mi = 0; mi < 8; ++mi) {
        const int row = m0 + wm * 128 + mi * 16 + (lane >> 4) * 4;
        #pragma unroll
        for (int nj = 0; nj < 4; ++nj) {
            const int col = n0 + wn * 64 + nj * 16 + fr;
            #pragma unroll
            for (int r = 0; r < 4; ++r)
                C[(size_t)(row + r) * N + col] = f2bf(acc[mi][nj][r]);
        }
    }
}

// ---------------------------------------------------------------------------
// m97-structure 128x128 bf16 GEMM (NT), fp32 out — used for GEMM2 (512 wgs).
// ---------------------------------------------------------------------------
__global__ __launch_bounds__(256) void gemm_bf16_nt(
    const unsigned short* __restrict__ A, const unsigned short* __restrict__ B,
    float* __restrict__ C, int M, int N, int K)
{
    __shared__ unsigned short As[128 * 32];
    __shared__ unsigned short Bs[128 * 32];

    const int tid  = threadIdx.x;
    const int wave = tid >> 6;
    const int lane = tid & 63;
    const int m0 = blockIdx.y * 128;
    const int n0 = blockIdx.x * 128;
    const int wr = wave >> 1, wc = wave & 1;

    const int srow = tid >> 2;
    const int scol = (tid & 3) * 8;
    const unsigned short* Ag = A + (size_t)(m0 + srow) * K + scol;
    const unsigned short* Bg = B + (size_t)(n0 + srow) * K + scol;
    char* AsW = (char*)As + wave * 1024;
    char* BsW = (char*)Bs + wave * 1024;

    f32x4 acc[4][4] = {};

    const int fr = lane & 15;
    const int fk = (lane >> 4) * 8;

    for (int k0 = 0; k0 < K; k0 += 32) {
        gload_lds16(Ag + k0,                  AsW);
        gload_lds16(Ag + k0 + (size_t)64 * K, AsW + 4096);
        gload_lds16(Bg + k0,                  BsW);
        gload_lds16(Bg + k0 + (size_t)64 * K, BsW + 4096);
        __syncthreads();

        bf16x8 af[4], bfr_[4];
        #pragma unroll
        for (int f = 0; f < 4; ++f) {
            af[f]   = *(const bf16x8*)&As[(wr * 64 + f * 16 + fr) * 32 + fk];
            bfr_[f] = *(const bf16x8*)&Bs[(wc * 64 + f * 16 + fr) * 32 + fk];
        }
        #pragma unroll
        for (int i = 0; i < 4; ++i)
            #pragma unroll
            for (int j = 0; j < 4; ++j)
                acc[i][j] = __builtin_amdgcn_mfma_f32_16x16x32_bf16(
                    af[i], bfr_[j], acc[i][j], 0, 0, 0);
        __syncthreads();
    }

    #pragma unroll
    for (int i = 0; i < 4; ++i) {
        const int row = m0 + wr * 64 + i * 16 + (lane >> 4) * 4;
        #pragma unroll
        for (int j = 0; j < 4; ++j) {
            const int col = n0 + wc * 64 + j * 16 + (lane & 15);
            #pragma unroll
            for (int r = 0; r < 4; ++r)
                C[(size_t)(row + r) * N + col] = acc[i][j][r];
        }
    }
}

// ---------------------------------------------------------------------------
// Segmented-parallel fused sigmoid(r)*WKV scan, bf16 in / bf16 out.
// Block = 512 thr = CHB(32) channels x SEG(16) segments; 32-lane group reads
// 64B contiguous per field. fp32 state throughout.
// ---------------------------------------------------------------------------
__global__ __launch_bounds__(512) void wkv_scan_par(
    const unsigned short* __restrict__ rkv,
    const float* __restrict__ td,  const float* __restrict__ tf,
    const float* __restrict__ tdr, const float* __restrict__ tfr,
    unsigned short* __restrict__ outcat)
{
    __shared__ float sBn[SEG][CHB], sBd[SEG][CHB], sMb[SEG][CHB];

    const int tid = threadIdx.x;
    const int ch  = tid & (CHB - 1);
    const int seg = tid >> 5;

    const int bi  = blockIdx.x;          // b(4) x dir(2) x cgroup(32)
    const int b   = bi >> 6;
    const int rem = bi & 63;
    const int dir = rem >> 5;
    const int c   = (rem & 31) * CHB + ch;

    const float w = -__expf(dir ? tdr[c] : td[c]);
    const float u = dir ? tfr[c] : tf[c];

    const int strideT = 6 * Cdim;
    const int tstep   = dir ? -strideT : strideT;
    const int t0      = dir ? (Tdim - 1 - seg * LSEG) : (seg * LSEG);

    const unsigned short* pbase = rkv + ((size_t)b * Tdim + t0) * strideT + dir * 3 * Cdim + c;

    const int PF = 4;

    // ---- phase 1: segment-local summary (k,v only) ----
    float bn = 0.0f, bd = 0.0f, mb = -1e38f;
    {
        const unsigned short* q = pbase;
        float kk[PF], vv[PF];
        #pragma unroll
        for (int i = 0; i < PF; ++i) {
            kk[i] = bf2f(q[Cdim]); vv[i] = bf2f(q[2 * Cdim]); q += tstep;
        }
        for (int t = 0; t < LSEG; t += PF) {
            float kn[PF], vn[PF];
            if (t + PF < LSEG) {
                #pragma unroll
                for (int i = 0; i < PF; ++i) {
                    kn[i] = bf2f(q[Cdim]); vn[i] = bf2f(q[2 * Cdim]); q += tstep;
                }
            }
            #pragma unroll
            for (int i = 0; i < PF; ++i) {
                const float k_ = kk[i], v_ = vv[i];
                const float mw = mb + w;
                const float mn = fmaxf(mw, k_);
                const float e1 = __expf(mw - mn);
                const float e2 = __expf(k_ - mn);
                bn = e1 * bn + e2 * v_;
                bd = e1 * bd + e2;
                mb = mn;
            }
            #pragma unroll
            for (int i = 0; i < PF; ++i) { kk[i] = kn[i]; vv[i] = vn[i]; }
        }
    }
    sBn[seg][ch] = bn; sBd[seg][ch] = bd; sMb[seg][ch] = mb;
    __syncthreads();

    // ---- phase 2: exclusive combine over segments ----
    if (tid < CHB) {
        float n = 0.0f, d = 0.0f, m = -1e38f;
        const float a = w * (float)LSEG;
        for (int s = 0; s < SEG; ++s) {
            const float tn = sBn[s][tid], tdn = sBd[s][tid], tm = sMb[s][tid];
            sBn[s][tid] = n; sBd[s][tid] = d; sMb[s][tid] = m;
            const float ma = m + a;
            const float mm = fmaxf(ma, tm);
            const float e1 = __expf(ma - mm);
            const float e2 = __expf(tm - mm);
            n = e1 * n + e2 * tn;
            d = e1 * d + e2 * tdn;
            m = mm;
        }
    }
    __syncthreads();

    // ---- phase 3: replay segment from prefix, emit outputs ----
    float num = sBn[seg][ch], den = sBd[seg][ch], mx = sMb[seg][ch];
    {
        const unsigned short* q = pbase;
        unsigned short* po = outcat + ((size_t)b * Tdim + t0) * (2 * Cdim) + dir * Cdim + c;
        const int ostep = dir ? -(2 * Cdim) : (2 * Cdim);

        float rr[PF], kk[PF], vv[PF];
        #pragma unroll
        for (int i = 0; i < PF; ++i) {
            rr[i] = bf2f(q[0]); kk[i] = bf2f(q[Cdim]); vv[i] = bf2f(q[2 * Cdim]); q += tstep;
        }
        for (int t = 0; t < LSEG; t += PF) {
            float rn[PF], kn[PF], vn[PF];
            if (t + PF < LSEG) {
                #pragma unroll
                for (int i = 0; i < PF; ++i) {
                    rn[i] = bf2f(q[0]); kn[i] = bf2f(q[Cdim]); vn[i] = bf2f(q[2 * Cdim]); q += tstep;
                }
            }
            #pragma unroll
            for (int i = 0; i < PF; ++i) {
                const float k_ = kk[i], v_ = vv[i], r_ = rr[i];
                const float ku = k_ + u;
                const float m  = fmaxf(mx, ku);
                const float e1 = __expf(mx - m);
                const float e2 = __expf(ku - m);
                const float y  = (e1 * num + e2 * v_) / (e1 * den + e2);
                const float sr = 1.0f / (1.0f + __expf(-r_));
                *po = f2bf(sr * y);
                po += ostep;
                const float mw  = mx + w;
                const float mn  = fmaxf(mw, k_);
                const float e1s = __expf(mw - mn);
                const float e2s = __expf(k_ - mn);
                num = e1s * num + e2s * v_;
                den = e1s * den + e2s;
                mx  = mn;
            }
            #pragma unroll
            for (int i = 0; i < PF; ++i) { rr[i] = rn[i]; kk[i] = kn[i]; vv[i] = vn[i]; }
        }
    }
}

// ---------------------------------------------------------------------------
extern "C" void kernel_launch(void* const* d_in, const int* in_sizes, int n_in,
                              void* d_out, int out_size, void* d_ws, size_t ws_size,
                              hipStream_t stream)
{
    const float* x    = (const float*)d_in[0];
    const float* rkvw = (const float*)d_in[1];
    const float* outw = (const float*)d_in[2];
    const float* td   = (const float*)d_in[3];
    const float* tf   = (const float*)d_in[4];
    const float* tdr  = (const float*)d_in[5];
    const float* tfr  = (const float*)d_in[6];
    float* out = (float*)d_out;

    const int M = Bdim * Tdim;   // 8192

    char* ws = (char*)d_ws;
    unsigned short* rkv = (unsigned short*)ws;                 //  96 MiB bf16 [B,T,6C]
    unsigned short* xb  = (unsigned short*)(ws + 100663296);   //  16 MiB bf16 x
    unsigned short* wb  = (unsigned short*)(ws + 117440512);   //  12 MiB bf16 rkv_w
    unsigned short* ob  = (unsigned short*)(ws + 130023424);   //   4 MiB bf16 out_w
    unsigned short* cat = (unsigned short*)(ws + 134217728);   //  32 MiB bf16 out_cat

    dim3 blk(256);

    hipLaunchKernelGGL(cast_f32_bf16, dim3((M * Cdim / 4 + 255) / 256), blk, 0, stream,
                       x, xb, M * Cdim / 4);
    hipLaunchKernelGGL(cast_f32_bf16, dim3((6 * Cdim * Cdim / 4 + 255) / 256), blk, 0, stream,
                       rkvw, wb, 6 * Cdim * Cdim / 4);
    hipLaunchKernelGGL(cast_f32_bf16, dim3((Cdim * 2 * Cdim / 4 + 255) / 256), blk, 0, stream,
                       outw, ob, Cdim * 2 * Cdim / 4);

    // GEMM1 (8-phase 256², bf16 out): M=8192, N=6144, K=1024; grid 768 (%8==0)
    hipLaunchKernelGGL(gemm_bf16_nt_256_obf, dim3((6 * Cdim / 256) * (M / 256)), dim3(512),
                       0, stream, xb, wb, rkv, M, 6 * Cdim, Cdim, 6 * Cdim / 256);

    // segmented-parallel fused sigmoid + bidirectional WKV scan (bf16 io)
    hipLaunchKernelGGL(wkv_scan_par, dim3(Bdim * 2 * (Cdim / CHB)), dim3(512), 0, stream,
                       rkv, td, tf, tdr, tfr, cat);

    // GEMM2 (m97 128², fp32 out): M=8192, N=1024, K=2048; grid 8x64=512
    hipLaunchKernelGGL(gemm_bf16_nt, dim3(Cdim / 128, M / 128), blk, 0, stream,
                       cat, ob, out, M, Cdim, 2 * Cdim);
}

// Round 6
// 253.496 us; speedup vs baseline: 7.8821x; 1.0227x over previous
//
#include <hip/hip_runtime.h>
#include <cstdint>
#include <cstddef>

#define Bdim 4
#define Tdim 2048
#define Cdim 1024

// scan geometry: block 1024 = CHB(32) channels x SEG(32) segments of LSEG(64)
#define SEG  32
#define CHB  32
#define LSEG (Tdim / SEG)

// GEMM1 persistent geometry
#define G1_K    1024
#define G1_GX   24        // N tiles (6144/256)
#define G1_CPX  96        // 768 tiles / 8 XCDs
#define G1_NIPT 8         // iterations per tile = K/128
#define G1_NITER 24       // 3 tiles * 8
#define G1_GMAX 47        // last global ktile index (48-1)

typedef __attribute__((ext_vector_type(8))) short bf16x8;
typedef __attribute__((ext_vector_type(4))) float f32x4;

__device__ __forceinline__ unsigned short f2bf(float f) {
    unsigned int u = __float_as_uint(f);
    u += 0x7fffu + ((u >> 16) & 1u);
    return (unsigned short)(u >> 16);
}
__device__ __forceinline__ float bf2f(unsigned short h) {
    return __uint_as_float((unsigned int)h << 16);
}

__device__ __forceinline__ void gload_lds16(const void* g, void* l) {
    __builtin_amdgcn_global_load_lds(
        (const __attribute__((address_space(1))) unsigned int*)g,
        (__attribute__((address_space(3))) unsigned int*)l,
        16, 0, 0);
}

// ---------------------------------------------------------------------------
// elementwise fp32 -> bf16 cast
// ---------------------------------------------------------------------------
__global__ __launch_bounds__(256) void cast_f32_bf16(
    const float* __restrict__ in, unsigned short* __restrict__ out, int n4)
{
    int i = blockIdx.x * 256 + threadIdx.x;
    if (i >= n4) return;
    float4 v = ((const float4*)in)[i];
    ushort4 o;
    o.x = f2bf(v.x); o.y = f2bf(v.y); o.z = f2bf(v.z); o.w = f2bf(v.w);
    ((ushort4*)out)[i] = o;
}

// ---------------------------------------------------------------------------
// Persistent 256x256 8-phase bf16 GEMM1 (NT), bf16 out.
// grid=256 blocks, each owns 3 tiles (768 total). Global ktile sequence
// g in [0,48): tile j=g>>4, kt=g&15. The vmcnt(8) pipeline runs continuously
// across tile boundaries (P3..P8 of a tile's last iteration stage the next
// tile's ktiles). Slots: {A,B} x {D=g&1} x {khalf}; schedule == R5 verified.
// Epilogue (store acc, zero acc) fires after i%8==7; subsequent vmcnt(8)
// conservatively drains the stores (bounded stall, correct).
// ---------------------------------------------------------------------------
__device__ __forceinline__ void stage_half(
    const unsigned short* __restrict__ G, int row0, int K, int elemoff,
    char* slot, int wave, int lane)
{
    const int sl = (lane & 3) ^ ((lane >> 3) & 3);
    const unsigned short* gp = G + (size_t)(row0 + wave * 16 + (lane >> 2)) * K
                                 + elemoff + sl * 8;
    gload_lds16(gp, slot + wave * 1024);
    gload_lds16(gp + (size_t)128 * K, slot + 8192 + wave * 1024);
}

#define GP(D, KH, MH, GPTR, ROW0, ELEMOFF, SSLOT, VM)                          \
  {                                                                            \
    const char* As_ = ldsb + (D)*32768 + (KH)*16384;                           \
    const char* Bs_ = ldsb + 65536 + (D)*32768 + (KH)*16384;                   \
    bf16x8 a_[4], b_[4];                                                       \
    _Pragma("unroll")                                                          \
    for (int i_ = 0; i_ < 4; ++i_)                                             \
      a_[i_] = *(const bf16x8*)(As_ + (wm*128 + ((MH)*4+i_)*16 + fr)*64 + cswz);\
    _Pragma("unroll")                                                          \
    for (int j_ = 0; j_ < 4; ++j_)                                             \
      b_[j_] = *(const bf16x8*)(Bs_ + (wn*64 + j_*16 + fr)*64 + cswz);         \
    stage_half(GPTR, ROW0, G1_K, ELEMOFF, SSLOT, wave, lane);                  \
    __builtin_amdgcn_s_barrier();                                              \
    __builtin_amdgcn_sched_barrier(0);                                         \
    __builtin_amdgcn_s_setprio(1);                                             \
    _Pragma("unroll")                                                          \
    for (int i_ = 0; i_ < 4; ++i_)                                             \
      _Pragma("unroll")                                                        \
      for (int j_ = 0; j_ < 4; ++j_)                                           \
        acc[(MH)*4+i_][j_] = __builtin_amdgcn_mfma_f32_16x16x32_bf16(          \
            a_[i_], b_[j_], acc[(MH)*4+i_][j_], 0, 0, 0);                      \
    __builtin_amdgcn_s_setprio(0);                                             \
    if (VM) { asm volatile("s_waitcnt vmcnt(8)" ::: "memory"); }               \
    __builtin_amdgcn_s_barrier();                                              \
    __builtin_amdgcn_sched_barrier(0);                                         \
  }

#define SELJ(j, a0, a1, a2) ((j) == 0 ? (a0) : ((j) == 1 ? (a1) : (a2)))

__global__ __launch_bounds__(512, 1) void gemm1_persist(
    const unsigned short* __restrict__ A, const unsigned short* __restrict__ B,
    unsigned short* __restrict__ C, int N)
{
    __shared__ char ldsbuf[131072];
    char* ldsb = ldsbuf;

    const int tid  = threadIdx.x;
    const int wave = tid >> 6;
    const int lane = tid & 63;
    const int wm = wave >> 2;
    const int wn = wave & 3;
    const int fr = lane & 15;
    const int cswz = (((lane >> 4) ^ ((fr >> 1) & 3)) << 4);

    // tile bases for this block's 3 tiles (XCD-swizzled flat 768-tile space)
    int m0j[1], n0j[1];  // (named scalars below; no dynamic arrays - rule #20)
    int m0_0, n0_0, m0_1, n0_1, m0_2, n0_2;
    {
        int vb, swz;
        vb = blockIdx.x;          swz = (vb & 7) * G1_CPX + (vb >> 3);
        m0_0 = (swz / G1_GX) * 256; n0_0 = (swz % G1_GX) * 256;
        vb = blockIdx.x + 256;    swz = (vb & 7) * G1_CPX + (vb >> 3);
        m0_1 = (swz / G1_GX) * 256; n0_1 = (swz % G1_GX) * 256;
        vb = blockIdx.x + 512;    swz = (vb & 7) * G1_CPX + (vb >> 3);
        m0_2 = (swz / G1_GX) * 256; n0_2 = (swz % G1_GX) * 256;
    }
    (void)m0j; (void)n0j;

    f32x4 acc[8][4] = {};

    // prologue: g=0 (k0,k1), g=1 (k0) for tile 0
    stage_half(A, m0_0, G1_K, 0,  ldsb + 0,             wave, lane);
    stage_half(B, n0_0, G1_K, 0,  ldsb + 65536,         wave, lane);
    stage_half(A, m0_0, G1_K, 32, ldsb + 16384,         wave, lane);
    stage_half(B, n0_0, G1_K, 32, ldsb + 65536 + 16384, wave, lane);
    stage_half(A, m0_0, G1_K, 64, ldsb + 32768,         wave, lane);
    stage_half(B, n0_0, G1_K, 64, ldsb + 65536 + 32768, wave, lane);
    asm volatile("s_waitcnt vmcnt(8)" ::: "memory");
    __builtin_amdgcn_s_barrier();
    __builtin_amdgcn_sched_barrier(0);

    for (int i = 0; i < G1_NITER; ++i) {
        const int jc  = i >> 3;                         // current tile
        int g2 = 2 * i + 2; if (g2 > G1_GMAX) g2 = G1_GMAX;
        int g3 = 2 * i + 3; if (g3 > G1_GMAX) g3 = G1_GMAX;
        const int j2 = g2 >> 4, kt2 = g2 & 15;
        const int j3 = g3 >> 4, kt3 = g3 & 15;
        const int kt1 = (2 * i + 1) & 15;

        const int m0c = SELJ(jc, m0_0, m0_1, m0_2);
        const int n0c = SELJ(jc, n0_0, n0_1, n0_2);
        const int m02 = SELJ(j2, m0_0, m0_1, m0_2);
        const int n02 = SELJ(j2, n0_0, n0_1, n0_2);
        const int m03 = SELJ(j3, m0_0, m0_1, m0_2);
        const int n03 = SELJ(j3, n0_0, n0_1, n0_2);

        GP(0, 0, 0, A, m0c, kt1 * 64 + 32, ldsb + 32768 + 16384,         0) // P1
        GP(0, 0, 1, B, n0c, kt1 * 64 + 32, ldsb + 65536 + 32768 + 16384, 1) // P2
        GP(0, 1, 0, A, m02, kt2 * 64,      ldsb + 0,                     0) // P3
        GP(0, 1, 1, B, n02, kt2 * 64,      ldsb + 65536,                 1) // P4
        GP(1, 0, 0, A, m02, kt2 * 64 + 32, ldsb + 16384,                 0) // P5
        GP(1, 0, 1, B, n02, kt2 * 64 + 32, ldsb + 65536 + 16384,         1) // P6
        GP(1, 1, 0, A, m03, kt3 * 64,      ldsb + 32768,                 0) // P7
        GP(1, 1, 1, B, n03, kt3 * 64,      ldsb + 65536 + 32768,         1) // P8

        if ((i & 7) == 7) {   // tile jc complete: store + reset acc
            #pragma unroll
            for (int mi = 0; mi < 8; ++mi) {
                const int row = m0c + wm * 128 + mi * 16 + (lane >> 4) * 4;
                #pragma unroll
                for (int nj = 0; nj < 4; ++nj) {
                    const int col = n0c + wn * 64 + nj * 16 + fr;
                    #pragma unroll
                    for (int r = 0; r < 4; ++r)
                        C[(size_t)(row + r) * N + col] = f2bf(acc[mi][nj][r]);
                }
            }
            #pragma unroll
            for (int mi = 0; mi < 8; ++mi)
                #pragma unroll
                for (int nj = 0; nj < 4; ++nj)
                    acc[mi][nj] = (f32x4){0.f, 0.f, 0.f, 0.f};
        }
    }
}

// ---------------------------------------------------------------------------
// m97-structure 128x128 bf16 GEMM (NT), fp32 out — GEMM2 (grid 512).
// ---------------------------------------------------------------------------
__global__ __launch_bounds__(256) void gemm_bf16_nt(
    const unsigned short* __restrict__ A, const unsigned short* __restrict__ B,
    float* __restrict__ C, int M, int N, int K)
{
    __shared__ unsigned short As[128 * 32];
    __shared__ unsigned short Bs[128 * 32];

    const int tid  = threadIdx.x;
    const int wave = tid >> 6;
    const int lane = tid & 63;
    const int m0 = blockIdx.y * 128;
    const int n0 = blockIdx.x * 128;
    const int wr = wave >> 1, wc = wave & 1;

    const int srow = tid >> 2;
    const int scol = (tid & 3) * 8;
    const unsigned short* Ag = A + (size_t)(m0 + srow) * K + scol;
    const unsigned short* Bg = B + (size_t)(n0 + srow) * K + scol;
    char* AsW = (char*)As + wave * 1024;
    char* BsW = (char*)Bs + wave * 1024;

    f32x4 acc[4][4] = {};

    const int fr = lane & 15;
    const int fk = (lane >> 4) * 8;

    for (int k0 = 0; k0 < K; k0 += 32) {
        gload_lds16(Ag + k0,                  AsW);
        gload_lds16(Ag + k0 + (size_t)64 * K, AsW + 4096);
        gload_lds16(Bg + k0,                  BsW);
        gload_lds16(Bg + k0 + (size_t)64 * K, BsW + 4096);
        __syncthreads();

        bf16x8 af[4], bfr_[4];
        #pragma unroll
        for (int f = 0; f < 4; ++f) {
            af[f]   = *(const bf16x8*)&As[(wr * 64 + f * 16 + fr) * 32 + fk];
            bfr_[f] = *(const bf16x8*)&Bs[(wc * 64 + f * 16 + fr) * 32 + fk];
        }
        #pragma unroll
        for (int i = 0; i < 4; ++i)
            #pragma unroll
            for (int j = 0; j < 4; ++j)
                acc[i][j] = __builtin_amdgcn_mfma_f32_16x16x32_bf16(
                    af[i], bfr_[j], acc[i][j], 0, 0, 0);
        __syncthreads();
    }

    #pragma unroll
    for (int i = 0; i < 4; ++i) {
        const int row = m0 + wr * 64 + i * 16 + (lane >> 4) * 4;
        #pragma unroll
        for (int j = 0; j < 4; ++j) {
            const int col = n0 + wc * 64 + j * 16 + (lane & 15);
            #pragma unroll
            for (int r = 0; r < 4; ++r)
                C[(size_t)(row + r) * N + col] = acc[i][j][r];
        }
    }
}

// ---------------------------------------------------------------------------
// Segmented-parallel fused sigmoid(r)*WKV scan, bf16 in / bf16 out.
// Block = 1024 thr = CHB(32) channels x SEG(32) segments of LSEG(64).
// PF=8 register prefetch (>=32B/lane in flight). fp32 state throughout.
// ---------------------------------------------------------------------------
__global__ __launch_bounds__(1024) void wkv_scan_par(
    const unsigned short* __restrict__ rkv,
    const float* __restrict__ td,  const float* __restrict__ tf,
    const float* __restrict__ tdr, const float* __restrict__ tfr,
    unsigned short* __restrict__ outcat)
{
    __shared__ float sBn[SEG][CHB], sBd[SEG][CHB], sMb[SEG][CHB];

    const int tid = threadIdx.x;
    const int ch  = tid & (CHB - 1);
    const int seg = tid >> 5;

    const int bi  = blockIdx.x;          // b(4) x dir(2) x cgroup(32)
    const int b   = bi >> 6;
    const int rem = bi & 63;
    const int dir = rem >> 5;
    const int c   = (rem & 31) * CHB + ch;

    const float w = -__expf(dir ? tdr[c] : td[c]);
    const float u = dir ? tfr[c] : tf[c];

    const int strideT = 6 * Cdim;
    const int tstep   = dir ? -strideT : strideT;
    const int t0      = dir ? (Tdim - 1 - seg * LSEG) : (seg * LSEG);

    const unsigned short* pbase = rkv + ((size_t)b * Tdim + t0) * strideT + dir * 3 * Cdim + c;

    const int PF = 8;

    // ---- phase 1: segment-local summary (k,v only) ----
    float bn = 0.0f, bd = 0.0f, mb = -1e38f;
    {
        const unsigned short* q = pbase;
        float kk[PF], vv[PF];
        #pragma unroll
        for (int i = 0; i < PF; ++i) {
            kk[i] = bf2f(q[Cdim]); vv[i] = bf2f(q[2 * Cdim]); q += tstep;
        }
        for (int t = 0; t < LSEG; t += PF) {
            float kn[PF], vn[PF];
            if (t + PF < LSEG) {
                #pragma unroll
                for (int i = 0; i < PF; ++i) {
                    kn[i] = bf2f(q[Cdim]); vn[i] = bf2f(q[2 * Cdim]); q += tstep;
                }
            }
            #pragma unroll
            for (int i = 0; i < PF; ++i) {
                const float k_ = kk[i], v_ = vv[i];
                const float mw = mb + w;
                const float mn = fmaxf(mw, k_);
                const float e1 = __expf(mw - mn);
                const float e2 = __expf(k_ - mn);
                bn = e1 * bn + e2 * v_;
                bd = e1 * bd + e2;
                mb = mn;
            }
            #pragma unroll
            for (int i = 0; i < PF; ++i) { kk[i] = kn[i]; vv[i] = vn[i]; }
        }
    }
    sBn[seg][ch] = bn; sBd[seg][ch] = bd; sMb[seg][ch] = mb;
    __syncthreads();

    // ---- phase 2: exclusive combine over segments ----
    if (tid < CHB) {
        float n = 0.0f, d = 0.0f, m = -1e38f;
        const float a = w * (float)LSEG;
        for (int s = 0; s < SEG; ++s) {
            const float tn = sBn[s][tid], tdn = sBd[s][tid], tm = sMb[s][tid];
            sBn[s][tid] = n; sBd[s][tid] = d; sMb[s][tid] = m;
            const float ma = m + a;
            const float mm = fmaxf(ma, tm);
            const float e1 = __expf(ma - mm);
            const float e2 = __expf(tm - mm);
            n = e1 * n + e2 * tn;
            d = e1 * d + e2 * tdn;
            m = mm;
        }
    }
    __syncthreads();

    // ---- phase 3: replay segment from prefix, emit outputs ----
    float num = sBn[seg][ch], den = sBd[seg][ch], mx = sMb[seg][ch];
    {
        const unsigned short* q = pbase;
        unsigned short* po = outcat + ((size_t)b * Tdim + t0) * (2 * Cdim) + dir * Cdim + c;
        const int ostep = dir ? -(2 * Cdim) : (2 * Cdim);

        float rr[PF], kk[PF], vv[PF];
        #pragma unroll
        for (int i = 0; i < PF; ++i) {
            rr[i] = bf2f(q[0]); kk[i] = bf2f(q[Cdim]); vv[i] = bf2f(q[2 * Cdim]); q += tstep;
        }
        for (int t = 0; t < LSEG; t += PF) {
            float rn[PF], kn[PF], vn[PF];
            if (t + PF < LSEG) {
                #pragma unroll
                for (int i = 0; i < PF; ++i) {
                    rn[i] = bf2f(q[0]); kn[i] = bf2f(q[Cdim]); vn[i] = bf2f(q[2 * Cdim]); q += tstep;
                }
            }
            #pragma unroll
            for (int i = 0; i < PF; ++i) {
                const float k_ = kk[i], v_ = vv[i], r_ = rr[i];
                const float ku = k_ + u;
                const float m  = fmaxf(mx, ku);
                const float e1 = __expf(mx - m);
                const float e2 = __expf(ku - m);
                const float y  = (e1 * num + e2 * v_) / (e1 * den + e2);
                const float sr = 1.0f / (1.0f + __expf(-r_));
                *po = f2bf(sr * y);
                po += ostep;
                const float mw  = mx + w;
                const float mn  = fmaxf(mw, k_);
                const float e1s = __expf(mw - mn);
                const float e2s = __expf(k_ - mn);
                num = e1s * num + e2s * v_;
                den = e1s * den + e2s;
                mx  = mn;
            }
            #pragma unroll
            for (int i = 0; i < PF; ++i) { rr[i] = rn[i]; kk[i] = kn[i]; vv[i] = vn[i]; }
        }
    }
}

// ---------------------------------------------------------------------------
extern "C" void kernel_launch(void* const* d_in, const int* in_sizes, int n_in,
                              void* d_out, int out_size, void* d_ws, size_t ws_size,
                              hipStream_t stream)
{
    const float* x    = (const float*)d_in[0];
    const float* rkvw = (const float*)d_in[1];
    const float* outw = (const float*)d_in[2];
    const float* td   = (const float*)d_in[3];
    const float* tf   = (const float*)d_in[4];
    const float* tdr  = (const float*)d_in[5];
    const float* tfr  = (const float*)d_in[6];
    float* out = (float*)d_out;

    const int M = Bdim * Tdim;   // 8192

    char* ws = (char*)d_ws;
    unsigned short* rkv = (unsigned short*)ws;                 //  96 MiB bf16 [B,T,6C]
    unsigned short* xb  = (unsigned short*)(ws + 100663296);   //  16 MiB bf16 x
    unsigned short* wb  = (unsigned short*)(ws + 117440512);   //  12 MiB bf16 rkv_w
    unsigned short* ob  = (unsigned short*)(ws + 130023424);   //   4 MiB bf16 out_w
    unsigned short* cat = (unsigned short*)(ws + 134217728);   //  32 MiB bf16 out_cat

    dim3 blk(256);

    hipLaunchKernelGGL(cast_f32_bf16, dim3((M * Cdim / 4 + 255) / 256), blk, 0, stream,
                       x, xb, M * Cdim / 4);
    hipLaunchKernelGGL(cast_f32_bf16, dim3((6 * Cdim * Cdim / 4 + 255) / 256), blk, 0, stream,
                       rkvw, wb, 6 * Cdim * Cdim / 4);
    hipLaunchKernelGGL(cast_f32_bf16, dim3((Cdim * 2 * Cdim / 4 + 255) / 256), blk, 0, stream,
                       outw, ob, Cdim * 2 * Cdim / 4);

    // GEMM1 persistent: M=8192, N=6144, K=1024; grid 256, 3 tiles/block
    hipLaunchKernelGGL(gemm1_persist, dim3(256), dim3(512), 0, stream,
                       xb, wb, rkv, 6 * Cdim);

    // segmented-parallel fused sigmoid + bidirectional WKV scan
    hipLaunchKernelGGL(wkv_scan_par, dim3(Bdim * 2 * (Cdim / CHB)), dim3(1024), 0, stream,
                       rkv, td, tf, tdr, tfr, cat);

    // GEMM2 (m97 128², fp32 out): M=8192, N=1024, K=2048; grid 8x64=512
    hipLaunchKernelGGL(gemm_bf16_nt, dim3(Cdim / 128, M / 128), blk, 0, stream,
                       cat, ob, out, M, Cdim, 2 * Cdim);
}

// Round 7
// 252.022 us; speedup vs baseline: 7.9282x; 1.0058x over previous
//
#include <hip/hip_runtime.h>
#include <cstdint>
#include <cstddef>

#define Bdim 4
#define Tdim 2048
#define Cdim 1024

// scan geometry: block 1024 = CHB(32) channels x SEG(32) segments of LSEG(64)
#define SEG  32
#define CHB  32
#define LSEG (Tdim / SEG)

// GEMM1 persistent geometry
#define G1_K    1024
#define G1_GX   24        // N tiles (6144/256)
#define G1_CPX  96        // 768 tiles / 8 XCDs
#define G1_NITER 24       // 3 tiles * 8 iterations
#define G1_GMAX 47        // last global ktile index

typedef __attribute__((ext_vector_type(8))) short bf16x8;
typedef __attribute__((ext_vector_type(4))) float f32x4;

__device__ __forceinline__ unsigned short f2bf(float f) {
    unsigned int u = __float_as_uint(f);
    u += 0x7fffu + ((u >> 16) & 1u);
    return (unsigned short)(u >> 16);
}
__device__ __forceinline__ float bf2f(unsigned short h) {
    return __uint_as_float((unsigned int)h << 16);
}

__device__ __forceinline__ void gload_lds16(const void* g, void* l) {
    __builtin_amdgcn_global_load_lds(
        (const __attribute__((address_space(1))) unsigned int*)g,
        (__attribute__((address_space(3))) unsigned int*)l,
        16, 0, 0);
}

// ---------------------------------------------------------------------------
// elementwise fp32 -> bf16 cast
// ---------------------------------------------------------------------------
__global__ __launch_bounds__(256) void cast_f32_bf16(
    const float* __restrict__ in, unsigned short* __restrict__ out, int n4)
{
    int i = blockIdx.x * 256 + threadIdx.x;
    if (i >= n4) return;
    float4 v = ((const float4*)in)[i];
    ushort4 o;
    o.x = f2bf(v.x); o.y = f2bf(v.y); o.z = f2bf(v.z); o.w = f2bf(v.w);
    ((ushort4*)out)[i] = o;
}

// ---------------------------------------------------------------------------
// Persistent 256x256 8-phase bf16 GEMM1 (NT), bf16 out. R6 skeleton; phases
// split GPAB/GPA: odd phase reads A(MH0)+B and does MH0 MFMAs, even phase
// reads A(MH1) only, REUSES B regs (LDS reads 32->24 per K-tile per wave).
// Staging slots / barrier / vmcnt(8) cadence identical to R4/R5/R6 (verified);
// reads only moved earlier relative to re-stage => same safety margins.
// ---------------------------------------------------------------------------
__device__ __forceinline__ void stage_half(
    const unsigned short* __restrict__ G, int row0, int K, int elemoff,
    char* slot, int wave, int lane)
{
    const int sl = (lane & 3) ^ ((lane >> 3) & 3);
    const unsigned short* gp = G + (size_t)(row0 + wave * 16 + (lane >> 2)) * K
                                 + elemoff + sl * 8;
    gload_lds16(gp, slot + wave * 1024);
    gload_lds16(gp + (size_t)128 * K, slot + 8192 + wave * 1024);
}

// odd phase: read A(MH0) + B, stage one A-half, MFMA MH0 (no vmcnt)
#define GPAB(D, KH, GPTR, ROW0, ELEMOFF, SSLOT)                                \
  {                                                                            \
    const char* As_ = ldsb + (D)*32768 + (KH)*16384;                           \
    const char* Bs_ = ldsb + 65536 + (D)*32768 + (KH)*16384;                   \
    bf16x8 a_[4];                                                              \
    _Pragma("unroll")                                                          \
    for (int i_ = 0; i_ < 4; ++i_)                                             \
      a_[i_] = *(const bf16x8*)(As_ + (wm*128 + i_*16 + fr)*64 + cswz);        \
    _Pragma("unroll")                                                          \
    for (int j_ = 0; j_ < 4; ++j_)                                             \
      bq[j_] = *(const bf16x8*)(Bs_ + (wn*64 + j_*16 + fr)*64 + cswz);         \
    stage_half(GPTR, ROW0, G1_K, ELEMOFF, SSLOT, wave, lane);                  \
    __builtin_amdgcn_s_barrier();                                              \
    __builtin_amdgcn_sched_barrier(0);                                         \
    __builtin_amdgcn_s_setprio(1);                                             \
    _Pragma("unroll")                                                          \
    for (int i_ = 0; i_ < 4; ++i_)                                             \
      _Pragma("unroll")                                                        \
      for (int j_ = 0; j_ < 4; ++j_)                                           \
        acc[i_][j_] = __builtin_amdgcn_mfma_f32_16x16x32_bf16(                 \
            a_[i_], bq[j_], acc[i_][j_], 0, 0, 0);                             \
    __builtin_amdgcn_s_setprio(0);                                             \
    __builtin_amdgcn_s_barrier();                                              \
    __builtin_amdgcn_sched_barrier(0);                                         \
  }

// even phase: read A(MH1) only, reuse bq, stage one B-half, MFMA MH1, vmcnt(8)
#define GPA(D, KH, GPTR, ROW0, ELEMOFF, SSLOT)                                 \
  {                                                                            \
    const char* As_ = ldsb + (D)*32768 + (KH)*16384;                           \
    bf16x8 a_[4];                                                              \
    _Pragma("unroll")                                                          \
    for (int i_ = 0; i_ < 4; ++i_)                                             \
      a_[i_] = *(const bf16x8*)(As_ + (wm*128 + (64 + i_*16 + fr))*64 + cswz); \
    stage_half(GPTR, ROW0, G1_K, ELEMOFF, SSLOT, wave, lane);                  \
    __builtin_amdgcn_s_barrier();                                              \
    __builtin_amdgcn_sched_barrier(0);                                         \
    __builtin_amdgcn_s_setprio(1);                                             \
    _Pragma("unroll")                                                          \
    for (int i_ = 0; i_ < 4; ++i_)                                             \
      _Pragma("unroll")                                                        \
      for (int j_ = 0; j_ < 4; ++j_)                                           \
        acc[4+i_][j_] = __builtin_amdgcn_mfma_f32_16x16x32_bf16(               \
            a_[i_], bq[j_], acc[4+i_][j_], 0, 0, 0);                           \
    __builtin_amdgcn_s_setprio(0);                                             \
    asm volatile("s_waitcnt vmcnt(8)" ::: "memory");                           \
    __builtin_amdgcn_s_barrier();                                              \
    __builtin_amdgcn_sched_barrier(0);                                         \
  }

#define SELJ(j, a0, a1, a2) ((j) == 0 ? (a0) : ((j) == 1 ? (a1) : (a2)))

__global__ __launch_bounds__(512, 1) void gemm1_persist(
    const unsigned short* __restrict__ A, const unsigned short* __restrict__ B,
    unsigned short* __restrict__ C, int N)
{
    __shared__ char ldsbuf[131072];
    char* ldsb = ldsbuf;

    const int tid  = threadIdx.x;
    const int wave = tid >> 6;
    const int lane = tid & 63;
    const int wm = wave >> 2;
    const int wn = wave & 3;
    const int fr = lane & 15;
    const int cswz = (((lane >> 4) ^ ((fr >> 1) & 3)) << 4);

    int m0_0, n0_0, m0_1, n0_1, m0_2, n0_2;
    {
        int vb, swz;
        vb = blockIdx.x;          swz = (vb & 7) * G1_CPX + (vb >> 3);
        m0_0 = (swz / G1_GX) * 256; n0_0 = (swz % G1_GX) * 256;
        vb = blockIdx.x + 256;    swz = (vb & 7) * G1_CPX + (vb >> 3);
        m0_1 = (swz / G1_GX) * 256; n0_1 = (swz % G1_GX) * 256;
        vb = blockIdx.x + 512;    swz = (vb & 7) * G1_CPX + (vb >> 3);
        m0_2 = (swz / G1_GX) * 256; n0_2 = (swz % G1_GX) * 256;
    }

    f32x4 acc[8][4] = {};

    // prologue: tile0 ktile0 (k0,k1) + ktile1 k0
    stage_half(A, m0_0, G1_K, 0,  ldsb + 0,             wave, lane);
    stage_half(B, n0_0, G1_K, 0,  ldsb + 65536,         wave, lane);
    stage_half(A, m0_0, G1_K, 32, ldsb + 16384,         wave, lane);
    stage_half(B, n0_0, G1_K, 32, ldsb + 65536 + 16384, wave, lane);
    stage_half(A, m0_0, G1_K, 64, ldsb + 32768,         wave, lane);
    stage_half(B, n0_0, G1_K, 64, ldsb + 65536 + 32768, wave, lane);
    asm volatile("s_waitcnt vmcnt(8)" ::: "memory");
    __builtin_amdgcn_s_barrier();
    __builtin_amdgcn_sched_barrier(0);

    for (int i = 0; i < G1_NITER; ++i) {
        const int jc  = i >> 3;
        int g2 = 2 * i + 2; if (g2 > G1_GMAX) g2 = G1_GMAX;
        int g3 = 2 * i + 3; if (g3 > G1_GMAX) g3 = G1_GMAX;
        const int j2 = g2 >> 4, kt2 = g2 & 15;
        const int j3 = g3 >> 4, kt3 = g3 & 15;
        const int kt1 = (2 * i + 1) & 15;

        const int m0c = SELJ(jc, m0_0, m0_1, m0_2);
        const int n0c = SELJ(jc, n0_0, n0_1, n0_2);
        const int m02 = SELJ(j2, m0_0, m0_1, m0_2);
        const int n02 = SELJ(j2, n0_0, n0_1, n0_2);
        const int m03 = SELJ(j3, m0_0, m0_1, m0_2);
        const int n03 = SELJ(j3, n0_0, n0_1, n0_2);

        bf16x8 bq[4];

        GPAB(0, 0, A, m0c, kt1 * 64 + 32, ldsb + 32768 + 16384)         // P1
        GPA (0, 0, B, n0c, kt1 * 64 + 32, ldsb + 65536 + 32768 + 16384) // P2
        GPAB(0, 1, A, m02, kt2 * 64,      ldsb + 0)                     // P3
        GPA (0, 1, B, n02, kt2 * 64,      ldsb + 65536)                 // P4
        GPAB(1, 0, A, m02, kt2 * 64 + 32, ldsb + 16384)                 // P5
        GPA (1, 0, B, n02, kt2 * 64 + 32, ldsb + 65536 + 16384)         // P6
        GPAB(1, 1, A, m03, kt3 * 64,      ldsb + 32768)                 // P7
        GPA (1, 1, B, n03, kt3 * 64,      ldsb + 65536 + 32768)         // P8

        if ((i & 7) == 7) {   // tile jc complete: store + reset acc
            #pragma unroll
            for (int mi = 0; mi < 8; ++mi) {
                const int row = m0c + wm * 128 + mi * 16 + (lane >> 4) * 4;
                #pragma unroll
                for (int nj = 0; nj < 4; ++nj) {
                    const int col = n0c + wn * 64 + nj * 16 + fr;
                    #pragma unroll
                    for (int r = 0; r < 4; ++r)
                        C[(size_t)(row + r) * N + col] = f2bf(acc[mi][nj][r]);
                }
            }
            #pragma unroll
            for (int mi = 0; mi < 8; ++mi)
                #pragma unroll
                for (int nj = 0; nj < 4; ++nj)
                    acc[mi][nj] = (f32x4){0.f, 0.f, 0.f, 0.f};
        }
    }
}

// ---------------------------------------------------------------------------
// m97-structure 128x128 bf16 GEMM (NT), fp32 out — GEMM2 (grid 512).
// ---------------------------------------------------------------------------
__global__ __launch_bounds__(256) void gemm_bf16_nt(
    const unsigned short* __restrict__ A, const unsigned short* __restrict__ B,
    float* __restrict__ C, int M, int N, int K)
{
    __shared__ unsigned short As[128 * 32];
    __shared__ unsigned short Bs[128 * 32];

    const int tid  = threadIdx.x;
    const int wave = tid >> 6;
    const int lane = tid & 63;
    const int m0 = blockIdx.y * 128;
    const int n0 = blockIdx.x * 128;
    const int wr = wave >> 1, wc = wave & 1;

    const int srow = tid >> 2;
    const int scol = (tid & 3) * 8;
    const unsigned short* Ag = A + (size_t)(m0 + srow) * K + scol;
    const unsigned short* Bg = B + (size_t)(n0 + srow) * K + scol;
    char* AsW = (char*)As + wave * 1024;
    char* BsW = (char*)Bs + wave * 1024;

    f32x4 acc[4][4] = {};

    const int fr = lane & 15;
    const int fk = (lane >> 4) * 8;

    for (int k0 = 0; k0 < K; k0 += 32) {
        gload_lds16(Ag + k0,                  AsW);
        gload_lds16(Ag + k0 + (size_t)64 * K, AsW + 4096);
        gload_lds16(Bg + k0,                  BsW);
        gload_lds16(Bg + k0 + (size_t)64 * K, BsW + 4096);
        __syncthreads();

        bf16x8 af[4], bfr_[4];
        #pragma unroll
        for (int f = 0; f < 4; ++f) {
            af[f]   = *(const bf16x8*)&As[(wr * 64 + f * 16 + fr) * 32 + fk];
            bfr_[f] = *(const bf16x8*)&Bs[(wc * 64 + f * 16 + fr) * 32 + fk];
        }
        #pragma unroll
        for (int i = 0; i < 4; ++i)
            #pragma unroll
            for (int j = 0; j < 4; ++j)
                acc[i][j] = __builtin_amdgcn_mfma_f32_16x16x32_bf16(
                    af[i], bfr_[j], acc[i][j], 0, 0, 0);
        __syncthreads();
    }

    #pragma unroll
    for (int i = 0; i < 4; ++i) {
        const int row = m0 + wr * 64 + i * 16 + (lane >> 4) * 4;
        #pragma unroll
        for (int j = 0; j < 4; ++j) {
            const int col = n0 + wc * 64 + j * 16 + (lane & 15);
            #pragma unroll
            for (int r = 0; r < 4; ++r)
                C[(size_t)(row + r) * N + col] = acc[i][j][r];
        }
    }
}

// ---------------------------------------------------------------------------
// Segmented-parallel fused sigmoid(r)*WKV scan, bf16 in / bf16 out.
// Block = 1024 thr = CHB(32) x SEG(32), LSEG=64, PF=8. fp32 state.
// ---------------------------------------------------------------------------
__global__ __launch_bounds__(1024) void wkv_scan_par(
    const unsigned short* __restrict__ rkv,
    const float* __restrict__ td,  const float* __restrict__ tf,
    const float* __restrict__ tdr, const float* __restrict__ tfr,
    unsigned short* __restrict__ outcat)
{
    __shared__ float sBn[SEG][CHB], sBd[SEG][CHB], sMb[SEG][CHB];

    const int tid = threadIdx.x;
    const int ch  = tid & (CHB - 1);
    const int seg = tid >> 5;

    const int bi  = blockIdx.x;
    const int b   = bi >> 6;
    const int rem = bi & 63;
    const int dir = rem >> 5;
    const int c   = (rem & 31) * CHB + ch;

    const float w = -__expf(dir ? tdr[c] : td[c]);
    const float u = dir ? tfr[c] : tf[c];

    const int strideT = 6 * Cdim;
    const int tstep   = dir ? -strideT : strideT;
    const int t0      = dir ? (Tdim - 1 - seg * LSEG) : (seg * LSEG);

    const unsigned short* pbase = rkv + ((size_t)b * Tdim + t0) * strideT + dir * 3 * Cdim + c;

    const int PF = 8;

    float bn = 0.0f, bd = 0.0f, mb = -1e38f;
    {
        const unsigned short* q = pbase;
        float kk[PF], vv[PF];
        #pragma unroll
        for (int i = 0; i < PF; ++i) {
            kk[i] = bf2f(q[Cdim]); vv[i] = bf2f(q[2 * Cdim]); q += tstep;
        }
        for (int t = 0; t < LSEG; t += PF) {
            float kn[PF], vn[PF];
            if (t + PF < LSEG) {
                #pragma unroll
                for (int i = 0; i < PF; ++i) {
                    kn[i] = bf2f(q[Cdim]); vn[i] = bf2f(q[2 * Cdim]); q += tstep;
                }
            }
            #pragma unroll
            for (int i = 0; i < PF; ++i) {
                const float k_ = kk[i], v_ = vv[i];
                const float mw = mb + w;
                const float mn = fmaxf(mw, k_);
                const float e1 = __expf(mw - mn);
                const float e2 = __expf(k_ - mn);
                bn = e1 * bn + e2 * v_;
                bd = e1 * bd + e2;
                mb = mn;
            }
            #pragma unroll
            for (int i = 0; i < PF; ++i) { kk[i] = kn[i]; vv[i] = vn[i]; }
        }
    }
    sBn[seg][ch] = bn; sBd[seg][ch] = bd; sMb[seg][ch] = mb;
    __syncthreads();

    if (tid < CHB) {
        float n = 0.0f, d = 0.0f, m = -1e38f;
        const float a = w * (float)LSEG;
        for (int s = 0; s < SEG; ++s) {
            const float tn = sBn[s][tid], tdn = sBd[s][tid], tm = sMb[s][tid];
            sBn[s][tid] = n; sBd[s][tid] = d; sMb[s][tid] = m;
            const float ma = m + a;
            const float mm = fmaxf(ma, tm);
            const float e1 = __expf(ma - mm);
            const float e2 = __expf(tm - mm);
            n = e1 * n + e2 * tn;
            d = e1 * d + e2 * tdn;
            m = mm;
        }
    }
    __syncthreads();

    float num = sBn[seg][ch], den = sBd[seg][ch], mx = sMb[seg][ch];
    {
        const unsigned short* q = pbase;
        unsigned short* po = outcat + ((size_t)b * Tdim + t0) * (2 * Cdim) + dir * Cdim + c;
        const int ostep = dir ? -(2 * Cdim) : (2 * Cdim);

        float rr[PF], kk[PF], vv[PF];
        #pragma unroll
        for (int i = 0; i < PF; ++i) {
            rr[i] = bf2f(q[0]); kk[i] = bf2f(q[Cdim]); vv[i] = bf2f(q[2 * Cdim]); q += tstep;
        }
        for (int t = 0; t < LSEG; t += PF) {
            float rn[PF], kn[PF], vn[PF];
            if (t + PF < LSEG) {
                #pragma unroll
                for (int i = 0; i < PF; ++i) {
                    rn[i] = bf2f(q[0]); kn[i] = bf2f(q[Cdim]); vn[i] = bf2f(q[2 * Cdim]); q += tstep;
                }
            }
            #pragma unroll
            for (int i = 0; i < PF; ++i) {
                const float k_ = kk[i], v_ = vv[i], r_ = rr[i];
                const float ku = k_ + u;
                const float m  = fmaxf(mx, ku);
                const float e1 = __expf(mx - m);
                const float e2 = __expf(ku - m);
                const float y  = (e1 * num + e2 * v_) / (e1 * den + e2);
                const float sr = 1.0f / (1.0f + __expf(-r_));
                *po = f2bf(sr * y);
                po += ostep;
                const float mw  = mx + w;
                const float mn  = fmaxf(mw, k_);
                const float e1s = __expf(mw - mn);
                const float e2s = __expf(k_ - mn);
                num = e1s * num + e2s * v_;
                den = e1s * den + e2s;
                mx  = mn;
            }
            #pragma unroll
            for (int i = 0; i < PF; ++i) { rr[i] = rn[i]; kk[i] = kn[i]; vv[i] = vn[i]; }
        }
    }
}

// ---------------------------------------------------------------------------
extern "C" void kernel_launch(void* const* d_in, const int* in_sizes, int n_in,
                              void* d_out, int out_size, void* d_ws, size_t ws_size,
                              hipStream_t stream)
{
    const float* x    = (const float*)d_in[0];
    const float* rkvw = (const float*)d_in[1];
    const float* outw = (const float*)d_in[2];
    const float* td   = (const float*)d_in[3];
    const float* tf   = (const float*)d_in[4];
    const float* tdr  = (const float*)d_in[5];
    const float* tfr  = (const float*)d_in[6];
    float* out = (float*)d_out;

    const int M = Bdim * Tdim;   // 8192

    char* ws = (char*)d_ws;
    unsigned short* rkv = (unsigned short*)ws;                 //  96 MiB bf16 [B,T,6C]
    unsigned short* xb  = (unsigned short*)(ws + 100663296);   //  16 MiB bf16 x
    unsigned short* wb  = (unsigned short*)(ws + 117440512);   //  12 MiB bf16 rkv_w
    unsigned short* ob  = (unsigned short*)(ws + 130023424);   //   4 MiB bf16 out_w
    unsigned short* cat = (unsigned short*)(ws + 134217728);   //  32 MiB bf16 out_cat

    dim3 blk(256);

    hipLaunchKernelGGL(cast_f32_bf16, dim3((M * Cdim / 4 + 255) / 256), blk, 0, stream,
                       x, xb, M * Cdim / 4);
    hipLaunchKernelGGL(cast_f32_bf16, dim3((6 * Cdim * Cdim / 4 + 255) / 256), blk, 0, stream,
                       rkvw, wb, 6 * Cdim * Cdim / 4);
    hipLaunchKernelGGL(cast_f32_bf16, dim3((Cdim * 2 * Cdim / 4 + 255) / 256), blk, 0, stream,
                       outw, ob, Cdim * 2 * Cdim / 4);

    // GEMM1 persistent: M=8192, N=6144, K=1024; grid 256, 3 tiles/block
    hipLaunchKernelGGL(gemm1_persist, dim3(256), dim3(512), 0, stream,
                       xb, wb, rkv, 6 * Cdim);

    // segmented-parallel fused sigmoid + bidirectional WKV scan
    hipLaunchKernelGGL(wkv_scan_par, dim3(Bdim * 2 * (Cdim / CHB)), dim3(1024), 0, stream,
                       rkv, td, tf, tdr, tfr, cat);

    // GEMM2 (m97 128², fp32 out): M=8192, N=1024, K=2048; grid 8x64=512
    hipLaunchKernelGGL(gemm_bf16_nt, dim3(Cdim / 128, M / 128), blk, 0, stream,
                       cat, ob, out, M, Cdim, 2 * Cdim);
}

// Round 8
// 251.970 us; speedup vs baseline: 7.9299x; 1.0002x over previous
//
#include <hip/hip_runtime.h>
#include <cstdint>
#include <cstddef>

#define Bdim 4
#define Tdim 2048
#define Cdim 1024

// scan geometry: block 1024 = CHB(32) channels x SEG(32) segments of LSEG(64)
#define SEG  32
#define CHB  32
#define LSEG (Tdim / SEG)

// GEMM1 persistent geometry
#define G1_K    1024
#define G1_GX   24        // N tiles (6144/256)
#define G1_CPX  96        // 768 tiles / 8 XCDs
#define G1_NITER 24       // 3 tiles * 8 iterations
#define G1_GMAX 47        // last global ktile index

typedef __attribute__((ext_vector_type(8))) short bf16x8;
typedef __attribute__((ext_vector_type(4))) float f32x4;

__device__ __forceinline__ unsigned short f2bf(float f) {
    unsigned int u = __float_as_uint(f);
    u += 0x7fffu + ((u >> 16) & 1u);
    return (unsigned short)(u >> 16);
}
__device__ __forceinline__ float bf2f(unsigned short h) {
    return __uint_as_float((unsigned int)h << 16);
}

__device__ __forceinline__ void gload_lds16(const void* g, void* l) {
    __builtin_amdgcn_global_load_lds(
        (const __attribute__((address_space(1))) unsigned int*)g,
        (__attribute__((address_space(3))) unsigned int*)l,
        16, 0, 0);
}

// ---------------------------------------------------------------------------
// elementwise fp32 -> bf16 cast
// ---------------------------------------------------------------------------
__global__ __launch_bounds__(256) void cast_f32_bf16(
    const float* __restrict__ in, unsigned short* __restrict__ out, int n4)
{
    int i = blockIdx.x * 256 + threadIdx.x;
    if (i >= n4) return;
    float4 v = ((const float4*)in)[i];
    ushort4 o;
    o.x = f2bf(v.x); o.y = f2bf(v.y); o.z = f2bf(v.z); o.w = f2bf(v.w);
    ((ushort4*)out)[i] = o;
}

// ---------------------------------------------------------------------------
// Persistent 256x256 8-phase bf16 GEMM1 (NT), bf16 out. R7 skeleton with
// CROSS-PHASE A-REGISTER PREFETCH: phase p issues ds_reads for phase p+1's
// A-fragments (double-buffered aX/aY); even phases have NO in-phase read
// dependency; odd phases wait only on their 4 B-reads (issued BEFORE the
// A-prefetch so the compiler's counted lgkm wait leaves the prefetch in
// flight under the MFMA burst). Staging slots / stage order / MFMA
// accumulation order identical to R7 (bit-identical output). Reads moved
// <=1 phase earlier => loop vmcnt tightened 8 -> 6 (re-verified per-slot:
// every read has >=1 vmcnt(6)-confirmation + barrier after its stage).
// ---------------------------------------------------------------------------
__device__ __forceinline__ void stage_half(
    const unsigned short* __restrict__ G, int row0, int K, int elemoff,
    char* slot, int wave, int lane)
{
    const int sl = (lane & 3) ^ ((lane >> 3) & 3);
    const unsigned short* gp = G + (size_t)(row0 + wave * 16 + (lane >> 2)) * K
                                 + elemoff + sl * 8;
    gload_lds16(gp, slot + wave * 1024);
    gload_lds16(gp + (size_t)128 * K, slot + 8192 + wave * 1024);
}

// read 4 A fragments from LDS slot (D,KH), row block MHOFF (0 or 64), into DST
#define RD_A(DST, D, KH, MHOFF)                                                \
  {                                                                            \
    const char* As_ = ldsb + (D)*32768 + (KH)*16384;                           \
    _Pragma("unroll")                                                          \
    for (int i_ = 0; i_ < 4; ++i_)                                             \
      DST[i_] = *(const bf16x8*)(As_ + (wm*128 + (MHOFF) + i_*16 + fr)*64 + cswz); \
  }
// read 4 B fragments from LDS slot (D,KH) into bq
#define RD_B(D, KH)                                                            \
  {                                                                            \
    const char* Bs_ = ldsb + 65536 + (D)*32768 + (KH)*16384;                   \
    _Pragma("unroll")                                                          \
    for (int j_ = 0; j_ < 4; ++j_)                                             \
      bq[j_] = *(const bf16x8*)(Bs_ + (wn*64 + j_*16 + fr)*64 + cswz);         \
  }
// 16 MFMAs: SRC x bq -> acc[ACCOFF..ACCOFF+3]
#define MM(SRC, ACCOFF)                                                        \
    __builtin_amdgcn_s_setprio(1);                                             \
    _Pragma("unroll")                                                          \
    for (int i_ = 0; i_ < 4; ++i_)                                             \
      _Pragma("unroll")                                                        \
      for (int j_ = 0; j_ < 4; ++j_)                                           \
        acc[(ACCOFF)+i_][j_] = __builtin_amdgcn_mfma_f32_16x16x32_bf16(        \
            SRC[i_], bq[j_], acc[(ACCOFF)+i_][j_], 0, 0, 0);                   \
    __builtin_amdgcn_s_setprio(0);

#define BARS  __builtin_amdgcn_s_barrier(); __builtin_amdgcn_sched_barrier(0);
#define VM6   asm volatile("s_waitcnt vmcnt(6)" ::: "memory");

#define SELJ(j, a0, a1, a2) ((j) == 0 ? (a0) : ((j) == 1 ? (a1) : (a2)))

__global__ __launch_bounds__(512, 1) void gemm1_persist(
    const unsigned short* __restrict__ A, const unsigned short* __restrict__ B,
    unsigned short* __restrict__ C, int N)
{
    __shared__ char ldsbuf[131072];
    char* ldsb = ldsbuf;

    const int tid  = threadIdx.x;
    const int wave = tid >> 6;
    const int lane = tid & 63;
    const int wm = wave >> 2;
    const int wn = wave & 3;
    const int fr = lane & 15;
    const int cswz = (((lane >> 4) ^ ((fr >> 1) & 3)) << 4);

    int m0_0, n0_0, m0_1, n0_1, m0_2, n0_2;
    {
        int vb, swz;
        vb = blockIdx.x;          swz = (vb & 7) * G1_CPX + (vb >> 3);
        m0_0 = (swz / G1_GX) * 256; n0_0 = (swz % G1_GX) * 256;
        vb = blockIdx.x + 256;    swz = (vb & 7) * G1_CPX + (vb >> 3);
        m0_1 = (swz / G1_GX) * 256; n0_1 = (swz % G1_GX) * 256;
        vb = blockIdx.x + 512;    swz = (vb & 7) * G1_CPX + (vb >> 3);
        m0_2 = (swz / G1_GX) * 256; n0_2 = (swz % G1_GX) * 256;
    }

    f32x4 acc[8][4] = {};
    bf16x8 aX[4], aY[4], bq[4];   // loop-carried fragment registers

    // prologue: tile0 ktile0 (k0,k1) + ktile1 k0
    stage_half(A, m0_0, G1_K, 0,  ldsb + 0,             wave, lane);
    stage_half(B, n0_0, G1_K, 0,  ldsb + 65536,         wave, lane);
    stage_half(A, m0_0, G1_K, 32, ldsb + 16384,         wave, lane);
    stage_half(B, n0_0, G1_K, 32, ldsb + 65536 + 16384, wave, lane);
    stage_half(A, m0_0, G1_K, 64, ldsb + 32768,         wave, lane);
    stage_half(B, n0_0, G1_K, 64, ldsb + 65536 + 32768, wave, lane);
    asm volatile("s_waitcnt vmcnt(8)" ::: "memory");   // A,B D0K0 arrived
    __builtin_amdgcn_s_barrier();
    __builtin_amdgcn_sched_barrier(0);
    RD_A(aX, 0, 0, 0)    // seed P1's operand (slot confirmed above)

    for (int i = 0; i < G1_NITER; ++i) {
        const int jc  = i >> 3;
        int g2 = 2 * i + 2; if (g2 > G1_GMAX) g2 = G1_GMAX;
        int g3 = 2 * i + 3; if (g3 > G1_GMAX) g3 = G1_GMAX;
        const int j2 = g2 >> 4, kt2 = g2 & 15;
        const int j3 = g3 >> 4, kt3 = g3 & 15;
        const int kt1 = (2 * i + 1) & 15;

        const int m0c = SELJ(jc, m0_0, m0_1, m0_2);
        const int n0c = SELJ(jc, n0_0, n0_1, n0_2);
        const int m02 = SELJ(j2, m0_0, m0_1, m0_2);
        const int n02 = SELJ(j2, n0_0, n0_1, n0_2);
        const int m03 = SELJ(j3, m0_0, m0_1, m0_2);
        const int n03 = SELJ(j3, n0_0, n0_1, n0_2);

        // P1: MFMA (0,0)MH0 w/ aX; issue bq<-B(0,0) first, then aY<-A(0,0)MH1
        RD_B(0, 0) RD_A(aY, 0, 0, 64)
        stage_half(A, m0c, G1_K, kt1 * 64 + 32, ldsb + 32768 + 16384, wave, lane);
        BARS  MM(aX, 0)  BARS
        // P2: MFMA (0,0)MH1 w/ aY+bq (no new deps); prefetch aX<-A(0,1)MH0
        RD_A(aX, 0, 1, 0)
        stage_half(B, n0c, G1_K, kt1 * 64 + 32, ldsb + 65536 + 32768 + 16384, wave, lane);
        BARS  MM(aY, 4)  VM6  BARS
        // P3: MFMA (0,1)MH0 w/ aX; bq<-B(0,1); aY<-A(0,1)MH1
        RD_B(0, 1) RD_A(aY, 0, 1, 64)
        stage_half(A, m02, G1_K, kt2 * 64, ldsb + 0, wave, lane);
        BARS  MM(aX, 0)  BARS
        // P4: MFMA (0,1)MH1; prefetch aX<-A(1,0)MH0
        RD_A(aX, 1, 0, 0)
        stage_half(B, n02, G1_K, kt2 * 64, ldsb + 65536, wave, lane);
        BARS  MM(aY, 4)  VM6  BARS
        // P5: MFMA (1,0)MH0; bq<-B(1,0); aY<-A(1,0)MH1
        RD_B(1, 0) RD_A(aY, 1, 0, 64)
        stage_half(A, m02, G1_K, kt2 * 64 + 32, ldsb + 16384, wave, lane);
        BARS  MM(aX, 0)  BARS
        // P6: MFMA (1,0)MH1; prefetch aX<-A(1,1)MH0
        RD_A(aX, 1, 1, 0)
        stage_half(B, n02, G1_K, kt2 * 64 + 32, ldsb + 65536 + 16384, wave, lane);
        BARS  MM(aY, 4)  VM6  BARS
        // P7: MFMA (1,1)MH0; bq<-B(1,1); aY<-A(1,1)MH1
        RD_B(1, 1) RD_A(aY, 1, 1, 64)
        stage_half(A, m03, G1_K, kt3 * 64, ldsb + 32768, wave, lane);
        BARS  MM(aX, 0)  BARS
        // P8: MFMA (1,1)MH1; prefetch aX<-A(0,0)MH0 (next k-tile pair,
        //     slot D0K0 staged at P3 this iteration, confirmed by P6/P8 VM6)
        RD_A(aX, 0, 0, 0)
        stage_half(B, n03, G1_K, kt3 * 64, ldsb + 65536 + 32768, wave, lane);
        BARS  MM(aY, 4)  VM6  BARS

        if ((i & 7) == 7) {   // tile jc complete: store + reset acc
            #pragma unroll
            for (int mi = 0; mi < 8; ++mi) {
                const int row = m0c + wm * 128 + mi * 16 + (lane >> 4) * 4;
                #pragma unroll
                for (int nj = 0; nj < 4; ++nj) {
                    const int col = n0c + wn * 64 + nj * 16 + fr;
                    #pragma unroll
                    for (int r = 0; r < 4; ++r)
                        C[(size_t)(row + r) * N + col] = f2bf(acc[mi][nj][r]);
                }
            }
            #pragma unroll
            for (int mi = 0; mi < 8; ++mi)
                #pragma unroll
                for (int nj = 0; nj < 4; ++nj)
                    acc[mi][nj] = (f32x4){0.f, 0.f, 0.f, 0.f};
        }
    }
}

// ---------------------------------------------------------------------------
// m97-structure 128x128 bf16 GEMM (NT), fp32 out — GEMM2 (grid 512).
// ---------------------------------------------------------------------------
__global__ __launch_bounds__(256) void gemm_bf16_nt(
    const unsigned short* __restrict__ A, const unsigned short* __restrict__ B,
    float* __restrict__ C, int M, int N, int K)
{
    __shared__ unsigned short As[128 * 32];
    __shared__ unsigned short Bs[128 * 32];

    const int tid  = threadIdx.x;
    const int wave = tid >> 6;
    const int lane = tid & 63;
    const int m0 = blockIdx.y * 128;
    const int n0 = blockIdx.x * 128;
    const int wr = wave >> 1, wc = wave & 1;

    const int srow = tid >> 2;
    const int scol = (tid & 3) * 8;
    const unsigned short* Ag = A + (size_t)(m0 + srow) * K + scol;
    const unsigned short* Bg = B + (size_t)(n0 + srow) * K + scol;
    char* AsW = (char*)As + wave * 1024;
    char* BsW = (char*)Bs + wave * 1024;

    f32x4 acc[4][4] = {};

    const int fr = lane & 15;
    const int fk = (lane >> 4) * 8;

    for (int k0 = 0; k0 < K; k0 += 32) {
        gload_lds16(Ag + k0,                  AsW);
        gload_lds16(Ag + k0 + (size_t)64 * K, AsW + 4096);
        gload_lds16(Bg + k0,                  BsW);
        gload_lds16(Bg + k0 + (size_t)64 * K, BsW + 4096);
        __syncthreads();

        bf16x8 af[4], bfr_[4];
        #pragma unroll
        for (int f = 0; f < 4; ++f) {
            af[f]   = *(const bf16x8*)&As[(wr * 64 + f * 16 + fr) * 32 + fk];
            bfr_[f] = *(const bf16x8*)&Bs[(wc * 64 + f * 16 + fr) * 32 + fk];
        }
        #pragma unroll
        for (int i = 0; i < 4; ++i)
            #pragma unroll
            for (int j = 0; j < 4; ++j)
                acc[i][j] = __builtin_amdgcn_mfma_f32_16x16x32_bf16(
                    af[i], bfr_[j], acc[i][j], 0, 0, 0);
        __syncthreads();
    }

    #pragma unroll
    for (int i = 0; i < 4; ++i) {
        const int row = m0 + wr * 64 + i * 16 + (lane >> 4) * 4;
        #pragma unroll
        for (int j = 0; j < 4; ++j) {
            const int col = n0 + wc * 64 + j * 16 + (lane & 15);
            #pragma unroll
            for (int r = 0; r < 4; ++r)
                C[(size_t)(row + r) * N + col] = acc[i][j][r];
        }
    }
}

// ---------------------------------------------------------------------------
// Segmented-parallel fused sigmoid(r)*WKV scan, bf16 in / bf16 out.
// Block = 1024 thr = CHB(32) x SEG(32), LSEG=64, PF=8. fp32 state.
// ---------------------------------------------------------------------------
__global__ __launch_bounds__(1024) void wkv_scan_par(
    const unsigned short* __restrict__ rkv,
    const float* __restrict__ td,  const float* __restrict__ tf,
    const float* __restrict__ tdr, const float* __restrict__ tfr,
    unsigned short* __restrict__ outcat)
{
    __shared__ float sBn[SEG][CHB], sBd[SEG][CHB], sMb[SEG][CHB];

    const int tid = threadIdx.x;
    const int ch  = tid & (CHB - 1);
    const int seg = tid >> 5;

    const int bi  = blockIdx.x;
    const int b   = bi >> 6;
    const int rem = bi & 63;
    const int dir = rem >> 5;
    const int c   = (rem & 31) * CHB + ch;

    const float w = -__expf(dir ? tdr[c] : td[c]);
    const float u = dir ? tfr[c] : tf[c];

    const int strideT = 6 * Cdim;
    const int tstep   = dir ? -strideT : strideT;
    const int t0      = dir ? (Tdim - 1 - seg * LSEG) : (seg * LSEG);

    const unsigned short* pbase = rkv + ((size_t)b * Tdim + t0) * strideT + dir * 3 * Cdim + c;

    const int PF = 8;

    float bn = 0.0f, bd = 0.0f, mb = -1e38f;
    {
        const unsigned short* q = pbase;
        float kk[PF], vv[PF];
        #pragma unroll
        for (int i = 0; i < PF; ++i) {
            kk[i] = bf2f(q[Cdim]); vv[i] = bf2f(q[2 * Cdim]); q += tstep;
        }
        for (int t = 0; t < LSEG; t += PF) {
            float kn[PF], vn[PF];
            if (t + PF < LSEG) {
                #pragma unroll
                for (int i = 0; i < PF; ++i) {
                    kn[i] = bf2f(q[Cdim]); vn[i] = bf2f(q[2 * Cdim]); q += tstep;
                }
            }
            #pragma unroll
            for (int i = 0; i < PF; ++i) {
                const float k_ = kk[i], v_ = vv[i];
                const float mw = mb + w;
                const float mn = fmaxf(mw, k_);
                const float e1 = __expf(mw - mn);
                const float e2 = __expf(k_ - mn);
                bn = e1 * bn + e2 * v_;
                bd = e1 * bd + e2;
                mb = mn;
            }
            #pragma unroll
            for (int i = 0; i < PF; ++i) { kk[i] = kn[i]; vv[i] = vn[i]; }
        }
    }
    sBn[seg][ch] = bn; sBd[seg][ch] = bd; sMb[seg][ch] = mb;
    __syncthreads();

    if (tid < CHB) {
        float n = 0.0f, d = 0.0f, m = -1e38f;
        const float a = w * (float)LSEG;
        for (int s = 0; s < SEG; ++s) {
            const float tn = sBn[s][tid], tdn = sBd[s][tid], tm = sMb[s][tid];
            sBn[s][tid] = n; sBd[s][tid] = d; sMb[s][tid] = m;
            const float ma = m + a;
            const float mm = fmaxf(ma, tm);
            const float e1 = __expf(ma - mm);
            const float e2 = __expf(tm - mm);
            n = e1 * n + e2 * tn;
            d = e1 * d + e2 * tdn;
            m = mm;
        }
    }
    __syncthreads();

    float num = sBn[seg][ch], den = sBd[seg][ch], mx = sMb[seg][ch];
    {
        const unsigned short* q = pbase;
        unsigned short* po = outcat + ((size_t)b * Tdim + t0) * (2 * Cdim) + dir * Cdim + c;
        const int ostep = dir ? -(2 * Cdim) : (2 * Cdim);

        float rr[PF], kk[PF], vv[PF];
        #pragma unroll
        for (int i = 0; i < PF; ++i) {
            rr[i] = bf2f(q[0]); kk[i] = bf2f(q[Cdim]); vv[i] = bf2f(q[2 * Cdim]); q += tstep;
        }
        for (int t = 0; t < LSEG; t += PF) {
            float rn[PF], kn[PF], vn[PF];
            if (t + PF < LSEG) {
                #pragma unroll
                for (int i = 0; i < PF; ++i) {
                    rn[i] = bf2f(q[0]); kn[i] = bf2f(q[Cdim]); vn[i] = bf2f(q[2 * Cdim]); q += tstep;
                }
            }
            #pragma unroll
            for (int i = 0; i < PF; ++i) {
                const float k_ = kk[i], v_ = vv[i], r_ = rr[i];
                const float ku = k_ + u;
                const float m  = fmaxf(mx, ku);
                const float e1 = __expf(mx - m);
                const float e2 = __expf(ku - m);
                const float y  = (e1 * num + e2 * v_) / (e1 * den + e2);
                const float sr = 1.0f / (1.0f + __expf(-r_));
                *po = f2bf(sr * y);
                po += ostep;
                const float mw  = mx + w;
                const float mn  = fmaxf(mw, k_);
                const float e1s = __expf(mw - mn);
                const float e2s = __expf(k_ - mn);
                num = e1s * num + e2s * v_;
                den = e1s * den + e2s;
                mx  = mn;
            }
            #pragma unroll
            for (int i = 0; i < PF; ++i) { rr[i] = rn[i]; kk[i] = kn[i]; vv[i] = vn[i]; }
        }
    }
}

// ---------------------------------------------------------------------------
extern "C" void kernel_launch(void* const* d_in, const int* in_sizes, int n_in,
                              void* d_out, int out_size, void* d_ws, size_t ws_size,
                              hipStream_t stream)
{
    const float* x    = (const float*)d_in[0];
    const float* rkvw = (const float*)d_in[1];
    const float* outw = (const float*)d_in[2];
    const float* td   = (const float*)d_in[3];
    const float* tf   = (const float*)d_in[4];
    const float* tdr  = (const float*)d_in[5];
    const float* tfr  = (const float*)d_in[6];
    float* out = (float*)d_out;

    const int M = Bdim * Tdim;   // 8192

    char* ws = (char*)d_ws;
    unsigned short* rkv = (unsigned short*)ws;                 //  96 MiB bf16 [B,T,6C]
    unsigned short* xb  = (unsigned short*)(ws + 100663296);   //  16 MiB bf16 x
    unsigned short* wb  = (unsigned short*)(ws + 117440512);   //  12 MiB bf16 rkv_w
    unsigned short* ob  = (unsigned short*)(ws + 130023424);   //   4 MiB bf16 out_w
    unsigned short* cat = (unsigned short*)(ws + 134217728);   //  32 MiB bf16 out_cat

    dim3 blk(256);

    hipLaunchKernelGGL(cast_f32_bf16, dim3((M * Cdim / 4 + 255) / 256), blk, 0, stream,
                       x, xb, M * Cdim / 4);
    hipLaunchKernelGGL(cast_f32_bf16, dim3((6 * Cdim * Cdim / 4 + 255) / 256), blk, 0, stream,
                       rkvw, wb, 6 * Cdim * Cdim / 4);
    hipLaunchKernelGGL(cast_f32_bf16, dim3((Cdim * 2 * Cdim / 4 + 255) / 256), blk, 0, stream,
                       outw, ob, Cdim * 2 * Cdim / 4);

    // GEMM1 persistent: M=8192, N=6144, K=1024; grid 256, 3 tiles/block
    hipLaunchKernelGGL(gemm1_persist, dim3(256), dim3(512), 0, stream,
                       xb, wb, rkv, 6 * Cdim);

    // segmented-parallel fused sigmoid + bidirectional WKV scan
    hipLaunchKernelGGL(wkv_scan_par, dim3(Bdim * 2 * (Cdim / CHB)), dim3(1024), 0, stream,
                       rkv, td, tf, tdr, tfr, cat);

    // GEMM2 (m97 128², fp32 out): M=8192, N=1024, K=2048; grid 8x64=512
    hipLaunchKernelGGL(gemm_bf16_nt, dim3(Cdim / 128, M / 128), blk, 0, stream,
                       cat, ob, out, M, Cdim, 2 * Cdim);
}

// Round 9
// 248.854 us; speedup vs baseline: 8.0292x; 1.0125x over previous
//
#include <hip/hip_runtime.h>
#include <cstdint>
#include <cstddef>

#define Bdim 4
#define Tdim 2048
#define Cdim 1024

// scan geometry: block 1024 = CHB(32) channels x SEG(32) segments of LSEG(64)
#define SEG  32
#define CHB  32
#define LSEG (Tdim / SEG)

// GEMM1 persistent geometry
#define G1_K    1024
#define G1_GX   24        // N tiles (6144/256)
#define G1_CPX  96        // 768 tiles / 8 XCDs
#define G1_NITER 24       // 3 tiles * 8 iterations
#define G1_GMAX 47        // last global ktile index

typedef __attribute__((ext_vector_type(8))) short bf16x8;
typedef __attribute__((ext_vector_type(4))) float f32x4;

__device__ __forceinline__ unsigned short f2bf(float f) {
    unsigned int u = __float_as_uint(f);
    u += 0x7fffu + ((u >> 16) & 1u);
    return (unsigned short)(u >> 16);
}
__device__ __forceinline__ float bf2f(unsigned short h) {
    return __uint_as_float((unsigned int)h << 16);
}

__device__ __forceinline__ void gload_lds16(const void* g, void* l) {
    __builtin_amdgcn_global_load_lds(
        (const __attribute__((address_space(1))) unsigned int*)g,
        (__attribute__((address_space(3))) unsigned int*)l,
        16, 0, 0);
}

// ---------------------------------------------------------------------------
// elementwise fp32 -> bf16 cast
// ---------------------------------------------------------------------------
__global__ __launch_bounds__(256) void cast_f32_bf16(
    const float* __restrict__ in, unsigned short* __restrict__ out, int n4)
{
    int i = blockIdx.x * 256 + threadIdx.x;
    if (i >= n4) return;
    float4 v = ((const float4*)in)[i];
    ushort4 o;
    o.x = f2bf(v.x); o.y = f2bf(v.y); o.z = f2bf(v.z); o.w = f2bf(v.w);
    ((ushort4*)out)[i] = o;
}

// ---------------------------------------------------------------------------
// Persistent 256x256 8-phase bf16 GEMM1 (NT), bf16 out.
// R9: FULL cross-phase fragment prefetch (A and B double-buffered in regs).
// Phase p issues ALL ds_reads for phase p+1 (4 or 8 b128), stages one
// half-tile, barrier, then MFMAs with registers read in phase p-1 -- the
// compiler's counted lgkmcnt(8) leaves the new reads in flight, so LDS
// service overlaps the MFMA burst (this was the serialized 60% of R6-R8).
//
// Read-safety re-derivation (reads moved 1 phase earlier than R4-R8):
// vmcnt tightened 6 -> 4 at P2/P4/P6/P8. Stage->read gaps (stage phase ->
// read phase, confirming VM4 in between, barrier after VM4 before read):
//   A/B-D0K0: staged P3/P4 -> read P8   (VM4@P6: newest4=P5,P6 => P3,P4 done)
//   A/B-D0K1: staged P5/P6 -> read P2'  (VM4@P8: newest4=P7,P8 => P5,P6 done)
//   A/B-D1K0: staged P7/P8 -> read P4'  (VM4@P2': newest4=P1',P2' => done)
//   A/B-D1K1: staged P1/P2 -> read P6   (VM4@P4: newest4=P3,P4 => P1,P2 done)
// vmcnt(4) semantics: counter decrements in issue order => "newest 4 remain"
// implies all older loads complete. Outstanding oscillates 4..8. Prologue:
// 12 loads then vmcnt(4) => loads 1-8 (D0K0+D0K1 A,B) complete before the
// seed reads and P1/P2 prefetches. MFMA accumulation order identical to
// R4-R8 => bit-identical output (absmax must remain exactly 0.0078125).
// ---------------------------------------------------------------------------
__device__ __forceinline__ void stage_half(
    const unsigned short* __restrict__ G, int row0, int K, int elemoff,
    char* slot, int wave, int lane)
{
    const int sl = (lane & 3) ^ ((lane >> 3) & 3);
    const unsigned short* gp = G + (size_t)(row0 + wave * 16 + (lane >> 2)) * K
                                 + elemoff + sl * 8;
    gload_lds16(gp, slot + wave * 1024);
    gload_lds16(gp + (size_t)128 * K, slot + 8192 + wave * 1024);
}

// read 4 A fragments from LDS slot (D,KH), row block MHOFF (0 or 64), into DST
#define RD_A(DST, D, KH, MHOFF)                                                \
  {                                                                            \
    const char* As_ = ldsb + (D)*32768 + (KH)*16384;                           \
    _Pragma("unroll")                                                          \
    for (int i_ = 0; i_ < 4; ++i_)                                             \
      DST[i_] = *(const bf16x8*)(As_ + (wm*128 + (MHOFF) + i_*16 + fr)*64 + cswz); \
  }
// read 4 B fragments from LDS slot (D,KH) into DST
#define RD_B(DST, D, KH)                                                       \
  {                                                                            \
    const char* Bs_ = ldsb + 65536 + (D)*32768 + (KH)*16384;                   \
    _Pragma("unroll")                                                          \
    for (int j_ = 0; j_ < 4; ++j_)                                             \
      DST[j_] = *(const bf16x8*)(Bs_ + (wn*64 + j_*16 + fr)*64 + cswz);        \
  }
// 16 MFMAs: SRCA x SRCB -> acc[ACCOFF..ACCOFF+3][0..3]
#define MM(SRCA, SRCB, ACCOFF)                                                 \
    __builtin_amdgcn_s_setprio(1);                                             \
    _Pragma("unroll")                                                          \
    for (int i_ = 0; i_ < 4; ++i_)                                             \
      _Pragma("unroll")                                                        \
      for (int j_ = 0; j_ < 4; ++j_)                                           \
        acc[(ACCOFF)+i_][j_] = __builtin_amdgcn_mfma_f32_16x16x32_bf16(        \
            SRCA[i_], SRCB[j_], acc[(ACCOFF)+i_][j_], 0, 0, 0);                \
    __builtin_amdgcn_s_setprio(0);

#define BARS  __builtin_amdgcn_s_barrier(); __builtin_amdgcn_sched_barrier(0);
#define VM4   asm volatile("s_waitcnt vmcnt(4)" ::: "memory");

#define SELJ(j, a0, a1, a2) ((j) == 0 ? (a0) : ((j) == 1 ? (a1) : (a2)))

__global__ __launch_bounds__(512, 1) void gemm1_persist(
    const unsigned short* __restrict__ A, const unsigned short* __restrict__ B,
    unsigned short* __restrict__ C, int N)
{
    __shared__ char ldsbuf[131072];
    char* ldsb = ldsbuf;

    const int tid  = threadIdx.x;
    const int wave = tid >> 6;
    const int lane = tid & 63;
    const int wm = wave >> 2;
    const int wn = wave & 3;
    const int fr = lane & 15;
    const int cswz = (((lane >> 4) ^ ((fr >> 1) & 3)) << 4);

    int m0_0, n0_0, m0_1, n0_1, m0_2, n0_2;
    {
        int vb, swz;
        vb = blockIdx.x;          swz = (vb & 7) * G1_CPX + (vb >> 3);
        m0_0 = (swz / G1_GX) * 256; n0_0 = (swz % G1_GX) * 256;
        vb = blockIdx.x + 256;    swz = (vb & 7) * G1_CPX + (vb >> 3);
        m0_1 = (swz / G1_GX) * 256; n0_1 = (swz % G1_GX) * 256;
        vb = blockIdx.x + 512;    swz = (vb & 7) * G1_CPX + (vb >> 3);
        m0_2 = (swz / G1_GX) * 256; n0_2 = (swz % G1_GX) * 256;
    }

    f32x4 acc[8][4] = {};
    bf16x8 aX[4], aY[4], bqX[4], bqY[4];   // loop-carried fragment registers

    // prologue: tile0 ktile0 (k0,k1) + ktile1 k0  (12 global_load_lds)
    stage_half(A, m0_0, G1_K, 0,  ldsb + 0,             wave, lane);
    stage_half(B, n0_0, G1_K, 0,  ldsb + 65536,         wave, lane);
    stage_half(A, m0_0, G1_K, 32, ldsb + 16384,         wave, lane);
    stage_half(B, n0_0, G1_K, 32, ldsb + 65536 + 16384, wave, lane);
    stage_half(A, m0_0, G1_K, 64, ldsb + 32768,         wave, lane);
    stage_half(B, n0_0, G1_K, 64, ldsb + 65536 + 32768, wave, lane);
    asm volatile("s_waitcnt vmcnt(4)" ::: "memory");   // D0K0+D0K1 A,B arrived
    __builtin_amdgcn_s_barrier();
    __builtin_amdgcn_sched_barrier(0);
    RD_A(aX, 0, 0, 0)      // seed P1 operands (slots confirmed above)
    RD_B(bqX, 0, 0)

    for (int i = 0; i < G1_NITER; ++i) {
        const int jc  = i >> 3;
        int g2 = 2 * i + 2; if (g2 > G1_GMAX) g2 = G1_GMAX;
        int g3 = 2 * i + 3; if (g3 > G1_GMAX) g3 = G1_GMAX;
        const int j2 = g2 >> 4, kt2 = g2 & 15;
        const int j3 = g3 >> 4, kt3 = g3 & 15;
        const int kt1 = (2 * i + 1) & 15;

        const int m0c = SELJ(jc, m0_0, m0_1, m0_2);
        const int n0c = SELJ(jc, n0_0, n0_1, n0_2);
        const int m02 = SELJ(j2, m0_0, m0_1, m0_2);
        const int n02 = SELJ(j2, n0_0, n0_1, n0_2);
        const int m03 = SELJ(j3, m0_0, m0_1, m0_2);
        const int n03 = SELJ(j3, n0_0, n0_1, n0_2);

        // P1: MFMA D0K0xMH0; prefetch aY<-A-D0K0-MH1
        RD_A(aY, 0, 0, 64)
        stage_half(A, m0c, G1_K, kt1 * 64 + 32, ldsb + 32768 + 16384, wave, lane);
        BARS  MM(aX, bqX, 0)  BARS
        // P2: MFMA D0K0xMH1; prefetch aX<-A-D0K1-MH0, bqY<-B-D0K1
        RD_A(aX, 0, 1, 0)  RD_B(bqY, 0, 1)
        stage_half(B, n0c, G1_K, kt1 * 64 + 32, ldsb + 65536 + 32768 + 16384, wave, lane);
        BARS  MM(aY, bqX, 4)  VM4  BARS
        // P3: MFMA D0K1xMH0; prefetch aY<-A-D0K1-MH1
        RD_A(aY, 0, 1, 64)
        stage_half(A, m02, G1_K, kt2 * 64, ldsb + 0, wave, lane);
        BARS  MM(aX, bqY, 0)  BARS
        // P4: MFMA D0K1xMH1; prefetch aX<-A-D1K0-MH0, bqX<-B-D1K0
        RD_A(aX, 1, 0, 0)  RD_B(bqX, 1, 0)
        stage_half(B, n02, G1_K, kt2 * 64, ldsb + 65536, wave, lane);
        BARS  MM(aY, bqY, 4)  VM4  BARS
        // P5: MFMA D1K0xMH0; prefetch aY<-A-D1K0-MH1
        RD_A(aY, 1, 0, 64)
        stage_half(A, m02, G1_K, kt2 * 64 + 32, ldsb + 16384, wave, lane);
        BARS  MM(aX, bqX, 0)  BARS
        // P6: MFMA D1K0xMH1; prefetch aX<-A-D1K1-MH0, bqY<-B-D1K1
        RD_A(aX, 1, 1, 0)  RD_B(bqY, 1, 1)
        stage_half(B, n02, G1_K, kt2 * 64 + 32, ldsb + 65536 + 16384, wave, lane);
        BARS  MM(aY, bqX, 4)  VM4  BARS
        // P7: MFMA D1K1xMH0; prefetch aY<-A-D1K1-MH1
        RD_A(aY, 1, 1, 64)
        stage_half(A, m03, G1_K, kt3 * 64, ldsb + 32768, wave, lane);
        BARS  MM(aX, bqY, 0)  BARS
        // P8: MFMA D1K1xMH1; prefetch aX<-A-D0K0'-MH0, bqX<-B-D0K0' (next pair)
        RD_A(aX, 0, 0, 0)  RD_B(bqX, 0, 0)
        stage_half(B, n03, G1_K, kt3 * 64, ldsb + 65536 + 32768, wave, lane);
        BARS  MM(aY, bqY, 4)  VM4  BARS

        if ((i & 7) == 7) {   // tile jc complete: store + reset acc
            #pragma unroll
            for (int mi = 0; mi < 8; ++mi) {
                const int row = m0c + wm * 128 + mi * 16 + (lane >> 4) * 4;
                #pragma unroll
                for (int nj = 0; nj < 4; ++nj) {
                    const int col = n0c + wn * 64 + nj * 16 + fr;
                    #pragma unroll
                    for (int r = 0; r < 4; ++r)
                        C[(size_t)(row + r) * N + col] = f2bf(acc[mi][nj][r]);
                }
            }
            #pragma unroll
            for (int mi = 0; mi < 8; ++mi)
                #pragma unroll
                for (int nj = 0; nj < 4; ++nj)
                    acc[mi][nj] = (f32x4){0.f, 0.f, 0.f, 0.f};
        }
    }
}

// ---------------------------------------------------------------------------
// m97-structure 128x128 bf16 GEMM (NT), fp32 out — GEMM2 (grid 512).
// ---------------------------------------------------------------------------
__global__ __launch_bounds__(256) void gemm_bf16_nt(
    const unsigned short* __restrict__ A, const unsigned short* __restrict__ B,
    float* __restrict__ C, int M, int N, int K)
{
    __shared__ unsigned short As[128 * 32];
    __shared__ unsigned short Bs[128 * 32];

    const int tid  = threadIdx.x;
    const int wave = tid >> 6;
    const int lane = tid & 63;
    const int m0 = blockIdx.y * 128;
    const int n0 = blockIdx.x * 128;
    const int wr = wave >> 1, wc = wave & 1;

    const int srow = tid >> 2;
    const int scol = (tid & 3) * 8;
    const unsigned short* Ag = A + (size_t)(m0 + srow) * K + scol;
    const unsigned short* Bg = B + (size_t)(n0 + srow) * K + scol;
    char* AsW = (char*)As + wave * 1024;
    char* BsW = (char*)Bs + wave * 1024;

    f32x4 acc[4][4] = {};

    const int fr = lane & 15;
    const int fk = (lane >> 4) * 8;

    for (int k0 = 0; k0 < K; k0 += 32) {
        gload_lds16(Ag + k0,                  AsW);
        gload_lds16(Ag + k0 + (size_t)64 * K, AsW + 4096);
        gload_lds16(Bg + k0,                  BsW);
        gload_lds16(Bg + k0 + (size_t)64 * K, BsW + 4096);
        __syncthreads();

        bf16x8 af[4], bfr_[4];
        #pragma unroll
        for (int f = 0; f < 4; ++f) {
            af[f]   = *(const bf16x8*)&As[(wr * 64 + f * 16 + fr) * 32 + fk];
            bfr_[f] = *(const bf16x8*)&Bs[(wc * 64 + f * 16 + fr) * 32 + fk];
        }
        #pragma unroll
        for (int i = 0; i < 4; ++i)
            #pragma unroll
            for (int j = 0; j < 4; ++j)
                acc[i][j] = __builtin_amdgcn_mfma_f32_16x16x32_bf16(
                    af[i], bfr_[j], acc[i][j], 0, 0, 0);
        __syncthreads();
    }

    #pragma unroll
    for (int i = 0; i < 4; ++i) {
        const int row = m0 + wr * 64 + i * 16 + (lane >> 4) * 4;
        #pragma unroll
        for (int j = 0; j < 4; ++j) {
            const int col = n0 + wc * 64 + j * 16 + (lane & 15);
            #pragma unroll
            for (int r = 0; r < 4; ++r)
                C[(size_t)(row + r) * N + col] = acc[i][j][r];
        }
    }
}

// ---------------------------------------------------------------------------
// Segmented-parallel fused sigmoid(r)*WKV scan, bf16 in / bf16 out.
// Block = 1024 thr = CHB(32) x SEG(32), LSEG=64, PF=8. fp32 state.
// ---------------------------------------------------------------------------
__global__ __launch_bounds__(1024) void wkv_scan_par(
    const unsigned short* __restrict__ rkv,
    const float* __restrict__ td,  const float* __restrict__ tf,
    const float* __restrict__ tdr, const float* __restrict__ tfr,
    unsigned short* __restrict__ outcat)
{
    __shared__ float sBn[SEG][CHB], sBd[SEG][CHB], sMb[SEG][CHB];

    const int tid = threadIdx.x;
    const int ch  = tid & (CHB - 1);
    const int seg = tid >> 5;

    const int bi  = blockIdx.x;
    const int b   = bi >> 6;
    const int rem = bi & 63;
    const int dir = rem >> 5;
    const int c   = (rem & 31) * CHB + ch;

    const float w = -__expf(dir ? tdr[c] : td[c]);
    const float u = dir ? tfr[c] : tf[c];

    const int strideT = 6 * Cdim;
    const int tstep   = dir ? -strideT : strideT;
    const int t0      = dir ? (Tdim - 1 - seg * LSEG) : (seg * LSEG);

    const unsigned short* pbase = rkv + ((size_t)b * Tdim + t0) * strideT + dir * 3 * Cdim + c;

    const int PF = 8;

    float bn = 0.0f, bd = 0.0f, mb = -1e38f;
    {
        const unsigned short* q = pbase;
        float kk[PF], vv[PF];
        #pragma unroll
        for (int i = 0; i < PF; ++i) {
            kk[i] = bf2f(q[Cdim]); vv[i] = bf2f(q[2 * Cdim]); q += tstep;
        }
        for (int t = 0; t < LSEG; t += PF) {
            float kn[PF], vn[PF];
            if (t + PF < LSEG) {
                #pragma unroll
                for (int i = 0; i < PF; ++i) {
                    kn[i] = bf2f(q[Cdim]); vn[i] = bf2f(q[2 * Cdim]); q += tstep;
                }
            }
            #pragma unroll
            for (int i = 0; i < PF; ++i) {
                const float k_ = kk[i], v_ = vv[i];
                const float mw = mb + w;
                const float mn = fmaxf(mw, k_);
                const float e1 = __expf(mw - mn);
                const float e2 = __expf(k_ - mn);
                bn = e1 * bn + e2 * v_;
                bd = e1 * bd + e2;
                mb = mn;
            }
            #pragma unroll
            for (int i = 0; i < PF; ++i) { kk[i] = kn[i]; vv[i] = vn[i]; }
        }
    }
    sBn[seg][ch] = bn; sBd[seg][ch] = bd; sMb[seg][ch] = mb;
    __syncthreads();

    if (tid < CHB) {
        float n = 0.0f, d = 0.0f, m = -1e38f;
        const float a = w * (float)LSEG;
        for (int s = 0; s < SEG; ++s) {
            const float tn = sBn[s][tid], tdn = sBd[s][tid], tm = sMb[s][tid];
            sBn[s][tid] = n; sBd[s][tid] = d; sMb[s][tid] = m;
            const float ma = m + a;
            const float mm = fmaxf(ma, tm);
            const float e1 = __expf(ma - mm);
            const float e2 = __expf(tm - mm);
            n = e1 * n + e2 * tn;
            d = e1 * d + e2 * tdn;
            m = mm;
        }
    }
    __syncthreads();

    float num = sBn[seg][ch], den = sBd[seg][ch], mx = sMb[seg][ch];
    {
        const unsigned short* q = pbase;
        unsigned short* po = outcat + ((size_t)b * Tdim + t0) * (2 * Cdim) + dir * Cdim + c;
        const int ostep = dir ? -(2 * Cdim) : (2 * Cdim);

        float rr[PF], kk[PF], vv[PF];
        #pragma unroll
        for (int i = 0; i < PF; ++i) {
            rr[i] = bf2f(q[0]); kk[i] = bf2f(q[Cdim]); vv[i] = bf2f(q[2 * Cdim]); q += tstep;
        }
        for (int t = 0; t < LSEG; t += PF) {
            float rn[PF], kn[PF], vn[PF];
            if (t + PF < LSEG) {
                #pragma unroll
                for (int i = 0; i < PF; ++i) {
                    rn[i] = bf2f(q[0]); kn[i] = bf2f(q[Cdim]); vn[i] = bf2f(q[2 * Cdim]); q += tstep;
                }
            }
            #pragma unroll
            for (int i = 0; i < PF; ++i) {
                const float k_ = kk[i], v_ = vv[i], r_ = rr[i];
                const float ku = k_ + u;
                const float m  = fmaxf(mx, ku);
                const float e1 = __expf(mx - m);
                const float e2 = __expf(ku - m);
                const float y  = (e1 * num + e2 * v_) / (e1 * den + e2);
                const float sr = 1.0f / (1.0f + __expf(-r_));
                *po = f2bf(sr * y);
                po += ostep;
                const float mw  = mx + w;
                const float mn  = fmaxf(mw, k_);
                const float e1s = __expf(mw - mn);
                const float e2s = __expf(k_ - mn);
                num = e1s * num + e2s * v_;
                den = e1s * den + e2s;
                mx  = mn;
            }
            #pragma unroll
            for (int i = 0; i < PF; ++i) { rr[i] = rn[i]; kk[i] = kn[i]; vv[i] = vn[i]; }
        }
    }
}

// ---------------------------------------------------------------------------
extern "C" void kernel_launch(void* const* d_in, const int* in_sizes, int n_in,
                              void* d_out, int out_size, void* d_ws, size_t ws_size,
                              hipStream_t stream)
{
    const float* x    = (const float*)d_in[0];
    const float* rkvw = (const float*)d_in[1];
    const float* outw = (const float*)d_in[2];
    const float* td   = (const float*)d_in[3];
    const float* tf   = (const float*)d_in[4];
    const float* tdr  = (const float*)d_in[5];
    const float* tfr  = (const float*)d_in[6];
    float* out = (float*)d_out;

    const int M = Bdim * Tdim;   // 8192

    char* ws = (char*)d_ws;
    unsigned short* rkv = (unsigned short*)ws;                 //  96 MiB bf16 [B,T,6C]
    unsigned short* xb  = (unsigned short*)(ws + 100663296);   //  16 MiB bf16 x
    unsigned short* wb  = (unsigned short*)(ws + 117440512);   //  12 MiB bf16 rkv_w
    unsigned short* ob  = (unsigned short*)(ws + 130023424);   //   4 MiB bf16 out_w
    unsigned short* cat = (unsigned short*)(ws + 134217728);   //  32 MiB bf16 out_cat

    dim3 blk(256);

    hipLaunchKernelGGL(cast_f32_bf16, dim3((M * Cdim / 4 + 255) / 256), blk, 0, stream,
                       x, xb, M * Cdim / 4);
    hipLaunchKernelGGL(cast_f32_bf16, dim3((6 * Cdim * Cdim / 4 + 255) / 256), blk, 0, stream,
                       rkvw, wb, 6 * Cdim * Cdim / 4);
    hipLaunchKernelGGL(cast_f32_bf16, dim3((Cdim * 2 * Cdim / 4 + 255) / 256), blk, 0, stream,
                       outw, ob, Cdim * 2 * Cdim / 4);

    // GEMM1 persistent: M=8192, N=6144, K=1024; grid 256, 3 tiles/block
    hipLaunchKernelGGL(gemm1_persist, dim3(256), dim3(512), 0, stream,
                       xb, wb, rkv, 6 * Cdim);

    // segmented-parallel fused sigmoid + bidirectional WKV scan
    hipLaunchKernelGGL(wkv_scan_par, dim3(Bdim * 2 * (Cdim / CHB)), dim3(1024), 0, stream,
                       rkv, td, tf, tdr, tfr, cat);

    // GEMM2 (m97 128², fp32 out): M=8192, N=1024, K=2048; grid 8x64=512
    hipLaunchKernelGGL(gemm_bf16_nt, dim3(Cdim / 128, M / 128), blk, 0, stream,
                       cat, ob, out, M, Cdim, 2 * Cdim);
}